// Round 10
// baseline (1165.129 us; speedup 1.0000x reference)
//
#include <hip/hip_runtime.h>
#include <hip/hip_bf16.h>
#include <hip/hip_fp16.h>

#define NN 1000000
#define EE 4000000
#define BB 1024
#define DIM 32
#define FXDIM 55
#define EMBD 128
#define VOCAB 26
#define LL 1000
#define NF 32
#define KK 8
#define CF 3872   // 32*121
#define BSH 12
#define NB 245          // ceil(NN / 4096)
#define ESLOT 20480     // padded records per bucket

typedef _Float16 f16x8 __attribute__((ext_vector_type(8)));
typedef float f32x4 __attribute__((ext_vector_type(4)));

// ---------------- CSR build: bucketed two-pass (write-coalescing-friendly) ----------------
__global__ __launch_bounds__(256) void k_bscatter(const int* __restrict__ src,
                                                  const int* __restrict__ dst,
                                                  int* __restrict__ bcur,
                                                  unsigned long long* __restrict__ ebuf) {
    __shared__ unsigned long long rec[4096];
    __shared__ short bid[4096];
    __shared__ int cnt[NB], pref[NB], gb[NB];
    __shared__ int sc[256];
    int t = threadIdx.x;
    for (int i = t; i < NB; i += 256) cnt[i] = 0;
    __syncthreads();
    size_t base = (size_t)blockIdx.x * 4096;
    int b_[16], s_[16], d_[16];
#pragma unroll
    for (int j = 0; j < 16; ++j) {
        size_t e = base + (size_t)j * 256 + t;
        if (e < EE) {
            int d = dst[e];
            b_[j] = d >> BSH;
            d_[j] = d;
            s_[j] = src[e];
            atomicAdd(&cnt[b_[j]], 1);
        } else b_[j] = -1;
    }
    __syncthreads();
    int v = (t < NB) ? cnt[t] : 0;
    sc[t] = v;
    __syncthreads();
    for (int off = 1; off < 256; off <<= 1) {
        int a = (t >= off) ? sc[t - off] : 0;
        __syncthreads();
        sc[t] += a;
        __syncthreads();
    }
    if (t < NB) {
        pref[t] = sc[t] - v;
        gb[t] = (v > 0) ? atomicAdd(&bcur[t], v) : 0;
        cnt[t] = 0;
    }
    __syncthreads();
#pragma unroll
    for (int j = 0; j < 16; ++j) {
        if (b_[j] >= 0) {
            int r = atomicAdd(&cnt[b_[j]], 1);
            int p = pref[b_[j]] + r;
            rec[p] = ((unsigned long long)(unsigned)d_[j] << 32) | (unsigned)s_[j];
            bid[p] = (short)b_[j];
        }
    }
    __syncthreads();
    int total = sc[NB - 1];
    for (int p = t; p < total; p += 256) {
        int b = bid[p];
        size_t gp = (size_t)b * ESLOT + gb[b] + (p - pref[b]);
        ebuf[gp] = rec[p];
    }
}

__global__ void k_bscan(const int* __restrict__ bcnt, int* __restrict__ bbase) {
    __shared__ int sh[256];
    int t = threadIdx.x;
    int v = (t < NB) ? bcnt[t] : 0;
    sh[t] = v;
    __syncthreads();
    for (int off = 1; off < 256; off <<= 1) {
        int a = (t >= off) ? sh[t - off] : 0;
        __syncthreads();
        sh[t] += a;
        __syncthreads();
    }
    if (t < NB) bbase[t] = sh[t] - v;
}

__global__ __launch_bounds__(256) void k_build(const unsigned long long* __restrict__ ebuf,
                                               const int* __restrict__ bbase,
                                               const int* __restrict__ bcnt,
                                               int* __restrict__ rowptr,
                                               int* __restrict__ col) {
    __shared__ int cnt[4096];
    __shared__ int pref[4096];
    __shared__ int part[256];
    int b = blockIdx.x, t = threadIdx.x;
    int n0 = b << BSH;
    int nmax = min(4096, NN - n0);
    for (int i = t; i < 4096; i += 256) cnt[i] = 0;
    __syncthreads();
    int e0 = bbase[b];
    int ne = bcnt[b];
    const unsigned long long* eb = ebuf + (size_t)b * ESLOT;
    for (int e = t; e < ne; e += 256) {
        int d = (int)(eb[e] >> 32) & 4095;
        atomicAdd(&cnt[d], 1);
    }
    __syncthreads();
    int s = 0, loc[16];
    int bi = t * 16;
#pragma unroll
    for (int j = 0; j < 16; ++j) { loc[j] = s; s += cnt[bi + j]; }
    part[t] = s;
    __syncthreads();
    for (int off = 1; off < 256; off <<= 1) {
        int a = (t >= off) ? part[t - off] : 0;
        __syncthreads();
        part[t] += a;
        __syncthreads();
    }
    int pb = part[t] - s;
#pragma unroll
    for (int j = 0; j < 16; ++j) pref[bi + j] = pb + loc[j];
    __syncthreads();
    for (int i = t; i < nmax; i += 256) rowptr[n0 + i] = e0 + pref[i];
    if (b == NB - 1 && t == 0) rowptr[NN] = EE;
    __syncthreads();
    for (int e = t; e < ne; e += 256) {
        unsigned long long r = eb[e];
        int d = (int)(r >> 32) & 4095;
        int p = atomicAdd(&pref[d], 1);
        col[e0 + p] = (int)(r & 0xffffffffu);
    }
}

// ---------------- w1 fragment prep for MFMA p1 (K padded 55 -> 64) ----------------
__global__ __launch_bounds__(64) void k_pfrag(const float* __restrict__ w1,
                                              __half* __restrict__ w1f) {
    int l = threadIdx.x;
    int kbase = (l >> 4) * 8;
    int jj = l & 15;
#pragma unroll
    for (int q = 0; q < 2; ++q) {
#pragma unroll
        for (int c = 0; c < 2; ++c) {
            __half v[8];
#pragma unroll
            for (int i = 0; i < 8; ++i) {
                int k = q * 32 + kbase + i;
                int j = c * 16 + jj;
                v[i] = (k < FXDIM) ? __float2half_rn(w1[k * 32 + j]) : __half(0.f);
            }
            *(uint4*)&w1f[(size_t)((q * 2 + c) * 64 + l) * 8] = *(const uint4*)v;
        }
    }
}

// ---------------- layer-1 projection p = xd @ w1 via MFMA (exactly-once reads) ----------------
__global__ __launch_bounds__(256) void k_p1(const float* __restrict__ xd,
                                            const __half* __restrict__ w1f,
                                            __half* __restrict__ out) {
    __shared__ float zb[4][16 * 36];
    int tid = threadIdx.x;
    int l = tid & 63;
    int wid = tid >> 6;
    int rowg = l >> 4;
    int lan16 = l & 15;
    f16x8 bw00 = __builtin_bit_cast(f16x8, *(const uint4*)&w1f[(size_t)(0 * 64 + l) * 8]);
    f16x8 bw01 = __builtin_bit_cast(f16x8, *(const uint4*)&w1f[(size_t)(1 * 64 + l) * 8]);
    f16x8 bw10 = __builtin_bit_cast(f16x8, *(const uint4*)&w1f[(size_t)(2 * 64 + l) * 8]);
    f16x8 bw11 = __builtin_bit_cast(f16x8, *(const uint4*)&w1f[(size_t)(3 * 64 + l) * 8]);
    float* zw = zb[wid];
    int gw = (blockIdx.x * 256 + tid) >> 6;
    int ngw = (gridDim.x * 256) >> 6;
    for (int t = gw; t < NN / 16; t += ngw) {
        int n0 = t * 16;
        const float* row = xd + (size_t)(n0 + lan16) * FXDIM;
        f16x8 a0, a1;
#pragma unroll
        for (int i = 0; i < 8; ++i) a0[i] = (_Float16)row[rowg * 8 + i];
#pragma unroll
        for (int i = 0; i < 8; ++i) {
            int k = 32 + rowg * 8 + i;
            a1[i] = (k < FXDIM) ? (_Float16)row[k] : (_Float16)0.f;
        }
        f32x4 h0, h1;
#pragma unroll
        for (int r = 0; r < 4; ++r) { h0[r] = 0.f; h1[r] = 0.f; }
        h0 = __builtin_amdgcn_mfma_f32_16x16x32_f16(a0, bw00, h0, 0, 0, 0);
        h1 = __builtin_amdgcn_mfma_f32_16x16x32_f16(a0, bw01, h1, 0, 0, 0);
        h0 = __builtin_amdgcn_mfma_f32_16x16x32_f16(a1, bw10, h0, 0, 0, 0);
        h1 = __builtin_amdgcn_mfma_f32_16x16x32_f16(a1, bw11, h1, 0, 0, 0);
#pragma unroll
        for (int r = 0; r < 4; ++r) {
            int nd = rowg * 4 + r;
            zw[nd * 36 + lan16] = h0[r];
            zw[nd * 36 + 16 + lan16] = h1[r];
        }
        int sn = l >> 2, sc = (l & 3) * 8;
        f32x4 hv0 = *(const f32x4*)&zw[sn * 36 + sc];
        f32x4 hv1 = *(const f32x4*)&zw[sn * 36 + sc + 4];
        __half hh[8];
#pragma unroll
        for (int i = 0; i < 4; ++i) {
            hh[i] = __float2half_rn(hv0[i]);
            hh[4 + i] = __float2half_rn(hv1[i]);
        }
        *(uint4*)(out + (size_t)(n0 + sn) * 32 + sc) = *(const uint4*)hh;
    }
}

// ---------------- per-layer weight fragment prep (BN folded into W1) ----------------
template <int FIRST>
__global__ __launch_bounds__(64) void k_wfrag(const float* __restrict__ aff,
                                              const float* __restrict__ w1,
                                              const float* __restrict__ w2,
                                              __half* __restrict__ wf1,
                                              __half* __restrict__ wf2,
                                              float* __restrict__ tv) {
    int l = threadIdx.x;
    int kbase = (l >> 4) * 8;
    int jj = l & 15;
#pragma unroll
    for (int c = 0; c < 2; ++c) {
        int j = c * 16 + jj;
        __half v1[8], v2[8];
#pragma unroll
        for (int i = 0; i < 8; ++i) {
            int k = kbase + i;
            float s = FIRST ? 1.f : aff[k];
            v1[i] = __float2half_rn(s * w1[k * 32 + j]);
            v2[i] = __float2half_rn(w2[k * 32 + j]);
        }
        *(uint4*)&wf1[(size_t)(c * 64 + l) * 8] = *(const uint4*)v1;
        *(uint4*)&wf2[(size_t)(c * 64 + l) * 8] = *(const uint4*)v2;
    }
    if (!FIRST && l < 32) {
        float acc = 0.f;
        for (int k = 0; k < 32; ++k) acc += aff[32 + k] * w1[k * 32 + l];
        tv[l] = acc;
    }
}

// ---------------- fused GIN layer: gather-agg (2-chain) + MFMA MLP + BN stats ----------------
template <int FIRST>
__global__ __launch_bounds__(256) void k_mlp(const __half* __restrict__ hsrc,
                                             const int* __restrict__ rowptr,
                                             const int* __restrict__ colidx,
                                             const __half* __restrict__ wf1,
                                             const __half* __restrict__ wf2,
                                             const float* __restrict__ tv,
                                             const float* __restrict__ b1,
                                             const float* __restrict__ b2,
                                             __half* __restrict__ hdst,
                                             float* __restrict__ partial) {
    __shared__ float zb[4][16 * 36];
    __shared__ float sred[4][64];
    int tid = threadIdx.x;
    int l = tid & 63;
    int wid = tid >> 6;
    int rowg = l >> 4;
    int lan16 = l & 15;

    f16x8 bw2_0 = __builtin_bit_cast(f16x8, *(const uint4*)&wf2[(size_t)(0 * 64 + l) * 8]);
    f16x8 bw2_1 = __builtin_bit_cast(f16x8, *(const uint4*)&wf2[(size_t)(1 * 64 + l) * 8]);
    f16x8 bw1_0{}, bw1_1{};
    float tv0 = 0.f, tv1 = 0.f, b1c0 = 0.f, b1c1 = 0.f;
    float b1v[8];
    if (FIRST) {
#pragma unroll
        for (int i = 0; i < 8; ++i) b1v[i] = b1[rowg * 8 + i];
    } else {
        bw1_0 = __builtin_bit_cast(f16x8, *(const uint4*)&wf1[(size_t)(0 * 64 + l) * 8]);
        bw1_1 = __builtin_bit_cast(f16x8, *(const uint4*)&wf1[(size_t)(1 * 64 + l) * 8]);
        tv0 = tv[lan16];
        tv1 = tv[16 + lan16];
        b1c0 = b1[lan16];
        b1c1 = b1[16 + lan16];
    }
    float b2c0 = b2[lan16], b2c1 = b2[16 + lan16];
    float* zw = zb[wid];
    float ps0 = 0.f, ps1 = 0.f, pq0 = 0.f, pq1 = 0.f;
    int gw = (blockIdx.x * 256 + tid) >> 6;
    int ngw = (gridDim.x * 256) >> 6;
    for (int t = gw; t < NN / 16; t += ngw) {
        int n0 = t * 16;
        int node = n0 + lan16;
        int r0 = rowptr[node], r1 = rowptr[node + 1];
        // gather: self + neighbors, f32 accumulate, 2 chains
        uint4 su = *(const uint4*)(hsrc + (size_t)node * 32 + rowg * 8);
        f16x8 sf = __builtin_bit_cast(f16x8, su);
        float a0[8], a1[8];
#pragma unroll
        for (int i = 0; i < 8; ++i) { a0[i] = (float)sf[i]; a1[i] = 0.f; }
        int e = r0;
        for (; e + 2 <= r1; e += 2) {
            int s0 = colidx[e], s1 = colidx[e + 1];
            uint4 u0 = *(const uint4*)(hsrc + (size_t)s0 * 32 + rowg * 8);
            uint4 u1 = *(const uint4*)(hsrc + (size_t)s1 * 32 + rowg * 8);
            f16x8 f0 = __builtin_bit_cast(f16x8, u0);
            f16x8 f1 = __builtin_bit_cast(f16x8, u1);
#pragma unroll
            for (int i = 0; i < 8; ++i) { a0[i] += (float)f0[i]; a1[i] += (float)f1[i]; }
        }
        if (e < r1) {
            uint4 u0 = *(const uint4*)(hsrc + (size_t)colidx[e] * 32 + rowg * 8);
            f16x8 f0 = __builtin_bit_cast(f16x8, u0);
#pragma unroll
            for (int i = 0; i < 8; ++i) a1[i] += (float)f0[i];
        }
        f16x8 za;
        if (FIRST) {
#pragma unroll
            for (int i = 0; i < 8; ++i)
                za[i] = (_Float16)fmaxf(a0[i] + a1[i] + b1v[i], 0.f);
        } else {
            f16x8 af;
#pragma unroll
            for (int i = 0; i < 8; ++i) af[i] = (_Float16)(a0[i] + a1[i]);
            int rbase = n0 + rowg * 4;
            int4 rv = *(const int4*)&rowptr[rbase];
            int rext = rowptr[rbase + 4];
            float c0 = (float)(rv.y - rv.x + 1);
            float c1 = (float)(rv.z - rv.y + 1);
            float c2 = (float)(rv.w - rv.z + 1);
            float c3 = (float)(rext - rv.w + 1);
            f32x4 ac0, ac1;
            ac0[0] = fmaf(c0, tv0, b1c0); ac1[0] = fmaf(c0, tv1, b1c1);
            ac0[1] = fmaf(c1, tv0, b1c0); ac1[1] = fmaf(c1, tv1, b1c1);
            ac0[2] = fmaf(c2, tv0, b1c0); ac1[2] = fmaf(c2, tv1, b1c1);
            ac0[3] = fmaf(c3, tv0, b1c0); ac1[3] = fmaf(c3, tv1, b1c1);
            ac0 = __builtin_amdgcn_mfma_f32_16x16x32_f16(af, bw1_0, ac0, 0, 0, 0);
            ac1 = __builtin_amdgcn_mfma_f32_16x16x32_f16(af, bw1_1, ac1, 0, 0, 0);
#pragma unroll
            for (int r = 0; r < 4; ++r) {
                int nd = rowg * 4 + r;
                zw[nd * 36 + lan16] = fmaxf(ac0[r], 0.f);
                zw[nd * 36 + 16 + lan16] = fmaxf(ac1[r], 0.f);
            }
            f32x4 z0 = *(const f32x4*)&zw[lan16 * 36 + rowg * 8];
            f32x4 z1 = *(const f32x4*)&zw[lan16 * 36 + rowg * 8 + 4];
#pragma unroll
            for (int i = 0; i < 4; ++i) {
                za[i] = (_Float16)z0[i];
                za[4 + i] = (_Float16)z1[i];
            }
        }
        f32x4 h0, h1;
#pragma unroll
        for (int r = 0; r < 4; ++r) { h0[r] = b2c0; h1[r] = b2c1; }
        h0 = __builtin_amdgcn_mfma_f32_16x16x32_f16(za, bw2_0, h0, 0, 0, 0);
        h1 = __builtin_amdgcn_mfma_f32_16x16x32_f16(za, bw2_1, h1, 0, 0, 0);
#pragma unroll
        for (int r = 0; r < 4; ++r) {
            float v0 = fmaxf(h0[r], 0.f);
            float v1 = fmaxf(h1[r], 0.f);
            ps0 += v0; pq0 += v0 * v0;
            ps1 += v1; pq1 += v1 * v1;
            int nd = rowg * 4 + r;
            zw[nd * 36 + lan16] = v0;
            zw[nd * 36 + 16 + lan16] = v1;
        }
        int sn = l >> 2, sc = (l & 3) * 8;
        f32x4 hv0 = *(const f32x4*)&zw[sn * 36 + sc];
        f32x4 hv1 = *(const f32x4*)&zw[sn * 36 + sc + 4];
        __half hh[8];
#pragma unroll
        for (int i = 0; i < 4; ++i) {
            hh[i] = __float2half_rn(hv0[i]);
            hh[4 + i] = __float2half_rn(hv1[i]);
        }
        *(uint4*)(hdst + (size_t)(n0 + sn) * 32 + sc) = *(const uint4*)hh;
    }
    // stats reduce
    ps0 += __shfl_xor(ps0, 16, 64); ps0 += __shfl_xor(ps0, 32, 64);
    ps1 += __shfl_xor(ps1, 16, 64); ps1 += __shfl_xor(ps1, 32, 64);
    pq0 += __shfl_xor(pq0, 16, 64); pq0 += __shfl_xor(pq0, 32, 64);
    pq1 += __shfl_xor(pq1, 16, 64); pq1 += __shfl_xor(pq1, 32, 64);
    if (l < 16) {
        sred[wid][lan16] = ps0;
        sred[wid][16 + lan16] = ps1;
        sred[wid][32 + lan16] = pq0;
        sred[wid][48 + lan16] = pq1;
    }
    __syncthreads();
    if (tid < 64) {
        float s = sred[0][tid] + sred[1][tid] + sred[2][tid] + sred[3][tid];
        partial[(size_t)blockIdx.x * 64 + tid] = s;
    }
}

// ---------------- finalize BN stats -> affine s,t (1 block/channel) ----------------
__global__ __launch_bounds__(256) void k_reduce(const float* __restrict__ partial, int nblocks,
                                                const float* __restrict__ g, const float* __restrict__ bt,
                                                float* __restrict__ aff) {
    int c = blockIdx.x;
    int t = threadIdx.x;
    double s = 0.0, q = 0.0;
    for (int b = t; b < nblocks; b += 256) {
        s += (double)partial[(size_t)b * 64 + c];
        q += (double)partial[(size_t)b * 64 + 32 + c];
    }
    __shared__ double shs[256], shq[256];
    shs[t] = s; shq[t] = q;
    __syncthreads();
    for (int off = 128; off; off >>= 1) {
        if (t < off) { shs[t] += shs[t + off]; shq[t] += shq[t + off]; }
        __syncthreads();
    }
    if (t == 0) {
        double mean = shs[0] / (double)NN;
        double var = shq[0] / (double)NN - mean * mean;
        float r = (float)rsqrt(var + 1e-5);
        float sv = g[c] * r;
        aff[c] = sv;
        aff[32 + c] = bt[c] - (float)mean * sv;
    }
}

// ---------------- pooling (xd_batch sorted -> run-length + atomics) ----------------
__global__ __launch_bounds__(256) void k_pool(const __half* __restrict__ h,
                                              const int* __restrict__ batch,
                                              float* __restrict__ ps) {
    int lane = threadIdx.x & 31;
    int g = threadIdx.x >> 5;
    const int chunk = (NN + gridDim.x - 1) / gridDim.x;
    int s0 = blockIdx.x * chunk;
    int s1 = min(NN, s0 + chunk);
    int curb = -1;
    float acc = 0.f;
    for (int i = s0 + g; i < s1; i += 8) {
        int b = batch[i];
        if (b != curb) {
            if (curb >= 0) atomicAdd(&ps[curb * 32 + lane], acc);
            acc = 0.f;
            curb = b;
        }
        acc += __half2float(h[(size_t)i * 32 + lane]);
    }
    if (curb >= 0) atomicAdd(&ps[curb * 32 + lane], acc);
}

__device__ int lowerb(const int* a, int n, int key) {
    int lo = 0, hi = n;
    while (lo < hi) {
        int m = (lo + hi) >> 1;
        if (a[m] < key) lo = m + 1;
        else hi = m;
    }
    return lo;
}

__global__ void k_counts(const int* __restrict__ batch, int* __restrict__ cnt) {
    int b = blockIdx.x * blockDim.x + threadIdx.x;
    if (b < BB) cnt[b] = lowerb(batch, NN, b + 1) - lowerb(batch, NN, b);
}

// ---------------- xdv = ReLU(pooled' @ fcd_w + fcd_b) ----------------
__global__ __launch_bounds__(128) void k_xdv(const float* __restrict__ ps,
                                             const int* __restrict__ cnt,
                                             const float* __restrict__ aff,
                                             const float* __restrict__ w,
                                             const float* __restrict__ bb,
                                             float* __restrict__ xdv) {
    int b = blockIdx.x;
    int j = threadIdx.x;
    __shared__ float p[32];
    if (j < 32) p[j] = aff[j] * ps[b * 32 + j] + (float)cnt[b] * aff[32 + j];
    __syncthreads();
    float acc = bb[j];
#pragma unroll
    for (int c = 0; c < 32; ++c) acc += p[c] * w[c * 128 + j];
    xdv[b * 128 + j] = fmaxf(acc, 0.f);
}

// ---------------- conv branch ----------------
__global__ void k_kT(const float* __restrict__ ck, float* __restrict__ kT) {
    int i = blockIdx.x;
    int t = threadIdx.x;
    int o = t >> 3, k = t & 7;
    kT[(size_t)i * 256 + t] = ck[(size_t)o * (LL * KK) + (size_t)i * KK + k];
}

// Bucket-sorted phase 1 (register accumulation, no LDS RMW) + broadcast phase 2.
__global__ __launch_bounds__(256) void k_conv(const int* __restrict__ xt,
                                              const float* __restrict__ kT,
                                              const float* __restrict__ emb,
                                              const float* __restrict__ cb,
                                              float* __restrict__ cbuf) {
    __shared__ float S[VOCAB * 256];        // 26.6 KB
    __shared__ unsigned short order[LL];    // 2 KB
    __shared__ int scnt[VOCAB], soff[VOCAB + 1], bcur2[VOCAB];
    int t = threadIdx.x;
    int b = blockIdx.x;
    if (t < VOCAB) { scnt[t] = 0; bcur2[t] = 0; }
    __syncthreads();
    const int* row = xt + (size_t)b * LL;
    int vi[4];
#pragma unroll
    for (int j = 0; j < 4; ++j) {
        int i = t * 4 + j;
        if (i < LL) {
            vi[j] = row[i];
            atomicAdd(&scnt[vi[j]], 1);
        } else vi[j] = -1;
    }
    __syncthreads();
    if (t == 0) {
        int run = 0;
#pragma unroll
        for (int v = 0; v < VOCAB; ++v) { soff[v] = run; run += scnt[v]; }
        soff[VOCAB] = LL;
    }
    __syncthreads();
#pragma unroll
    for (int j = 0; j < 4; ++j) {
        if (vi[j] >= 0) {
            int pos = atomicAdd(&bcur2[vi[j]], 1);
            order[soff[vi[j]] + pos] = (unsigned short)(t * 4 + j);
        }
    }
    __syncthreads();
    // phase 1: S[v][t] = sum over bucket_v of kT[i*256+t], register accum
    for (int v = 0; v < VOCAB; ++v) {
        int e0 = soff[v], e1 = soff[v + 1];
        float acc0 = 0.f, acc1 = 0.f;
        int e = e0;
        for (; e + 2 <= e1; e += 2) {
            int i0 = order[e], i1 = order[e + 1];
            acc0 += kT[(size_t)i0 * 256 + t];
            acc1 += kT[(size_t)i1 * 256 + t];
        }
        if (e < e1) acc0 += kT[(size_t)order[e] * 256 + t];
        S[v * 256 + t] = acc0 + acc1;
    }
    __syncthreads();
    // phase 2: out[o,h] = cb[o] + sum_v sum_k S[v,o,k] * emb[v,h+k]
    int h = t & 127, half = t >> 7;
    if (h < 121) {
        float acc[16];
        int o0 = half * 16;
#pragma unroll
        for (int o = 0; o < 16; ++o) acc[o] = cb[o0 + o];
        for (int v = 0; v < VOCAB; ++v) {
            float e[8];
#pragma unroll
            for (int k = 0; k < 8; ++k) e[k] = emb[v * EMBD + h + k];   // L1-resident
#pragma unroll
            for (int o = 0; o < 16; ++o) {
                float a = acc[o];
#pragma unroll
                for (int k = 0; k < 8; ++k) a += S[v * 256 + (o0 + o) * 8 + k] * e[k];
                acc[o] = a;
            }
        }
#pragma unroll
        for (int o = 0; o < 16; ++o)
            cbuf[(size_t)b * CF + (size_t)(o0 + o) * 121 + h] = acc[o];
    }
}

// ---------------- bias init ----------------
__global__ void k_binit(const float* __restrict__ bias, float* __restrict__ out, int mask) {
    int i = blockIdx.x * blockDim.x + threadIdx.x;
    out[i] = bias[i & mask];
}

// ---------------- xtv += c_tile @ w_tile (split-K, LDS-tiled, atomic accumulate) ----------------
__global__ __launch_bounds__(256) void k_xtv(const float* __restrict__ c,
                                             const float* __restrict__ w,
                                             float* __restrict__ xtv) {
    __shared__ float ct[16][484];
    int rb = blockIdx.x >> 3, kc = blockIdx.x & 7;
    int b0 = rb * 16, k0 = kc * 484;
    int tid = threadIdx.x;
#pragma unroll
    for (int r = 0; r < 16; ++r)
        for (int k = tid; k < 484; k += 256)
            ct[r][k] = c[(size_t)(b0 + r) * CF + k0 + k];
    __syncthreads();
    int j = tid & 127, rh = tid >> 7;
    float acc[8];
#pragma unroll
    for (int r = 0; r < 8; ++r) acc[r] = 0.f;
    const float2* ct2 = (const float2*)&ct[0][0];
    for (int k2 = 0; k2 < 242; ++k2) {
        float w0 = w[(size_t)(k0 + 2 * k2) * 128 + j];
        float w1 = w[(size_t)(k0 + 2 * k2 + 1) * 128 + j];
#pragma unroll
        for (int r = 0; r < 8; ++r) {
            float2 cv = ct2[(rh * 8 + r) * 242 + k2];
            acc[r] = fmaf(cv.x, w0, fmaf(cv.y, w1, acc[r]));
        }
    }
#pragma unroll
    for (int r = 0; r < 8; ++r)
        atomicAdd(&xtv[(size_t)(b0 + rh * 8 + r) * 128 + j], acc[r]);
}

// ---------------- classifier ----------------
__global__ __launch_bounds__(1024) void k_cls1(const float* __restrict__ xdv,
                                               const float* __restrict__ xtv,
                                               const float* __restrict__ w,
                                               const float* __restrict__ bb,
                                               float* __restrict__ h1) {
    __shared__ float X[8][256];
    int j = threadIdx.x;
    int b0 = blockIdx.x * 8;
    for (int idx = j; idx < 8 * 256; idx += 1024) {
        int r = idx >> 8, k = idx & 255;
        X[r][k] = (k < 128) ? xdv[(b0 + r) * 128 + k] : xtv[(b0 + r) * 128 + (k - 128)];
    }
    __syncthreads();
    float acc[8];
#pragma unroll
    for (int r = 0; r < 8; ++r) acc[r] = bb[j];
    for (int k = 0; k < 256; ++k) {
        float wv = w[(size_t)k * 1024 + j];
#pragma unroll
        for (int r = 0; r < 8; ++r) acc[r] += X[r][k] * wv;
    }
#pragma unroll
    for (int r = 0; r < 8; ++r) h1[(size_t)(b0 + r) * 1024 + j] = fmaxf(acc[r], 0.f);
}

__global__ __launch_bounds__(256) void k_cls2(const float* __restrict__ h1,
                                              const float* __restrict__ w,
                                              float* __restrict__ h2) {
    __shared__ float X[8][256];
    int rb = blockIdx.x >> 2, kc = blockIdx.x & 3;
    int b0 = rb * 8, k0 = kc * 256;
    int tid = threadIdx.x;
#pragma unroll
    for (int r = 0; r < 8; ++r)
        X[r][tid] = h1[(size_t)(b0 + r) * 1024 + k0 + tid];
    __syncthreads();
    int j = tid;
    float acc[8];
#pragma unroll
    for (int r = 0; r < 8; ++r) acc[r] = 0.f;
    const float2* X2 = (const float2*)&X[0][0];
    for (int k2 = 0; k2 < 128; ++k2) {
        float w0 = w[(size_t)(k0 + 2 * k2) * 256 + j];
        float w1 = w[(size_t)(k0 + 2 * k2 + 1) * 256 + j];
#pragma unroll
        for (int r = 0; r < 8; ++r) {
            float2 xv = X2[r * 128 + k2];
            acc[r] = fmaf(xv.x, w0, fmaf(xv.y, w1, acc[r]));
        }
    }
#pragma unroll
    for (int r = 0; r < 8; ++r)
        atomicAdd(&h2[(size_t)(b0 + r) * 256 + j], acc[r]);
}

__global__ __launch_bounds__(256) void k_cls3(const float* __restrict__ h2,
                                              const float* __restrict__ w,
                                              const float* __restrict__ bb,
                                              const float* __restrict__ y,
                                              float* __restrict__ dout) {
    int lane = threadIdx.x & 63;
    int b = (blockIdx.x * blockDim.x + threadIdx.x) >> 6;
    if (b >= BB) return;
    float acc = 0.f;
    for (int k = lane; k < 256; k += 64) acc += fmaxf(h2[(size_t)b * 256 + k], 0.f) * w[k];
#pragma unroll
    for (int off = 32; off; off >>= 1) acc += __shfl_xor(acc, off, 64);
    if (lane == 0) dout[b] = acc + bb[0];
    if (lane == 1) dout[BB + b] = y[b];
}

// ---------------- launch ----------------
extern "C" void kernel_launch(void* const* d_in, const int* in_sizes, int n_in,
                              void* d_out, int out_size, void* d_ws, size_t ws_size,
                              hipStream_t stream) {
    const float* xd = (const float*)d_in[0];
    const int* ei = (const int*)d_in[1];
    const int* batch = (const int*)d_in[2];
    const int* xt = (const int*)d_in[3];
    const float* y = (const float*)d_in[4];
    const float* g1w1 = (const float*)d_in[5];
    const float* g1b1 = (const float*)d_in[6];
    const float* g1w2 = (const float*)d_in[7];
    const float* g1b2 = (const float*)d_in[8];
    const float* grw1 = (const float*)d_in[9];
    const float* grb1 = (const float*)d_in[10];
    const float* grw2 = (const float*)d_in[11];
    const float* grb2 = (const float*)d_in[12];
    const float* bng = (const float*)d_in[13];
    const float* bnb = (const float*)d_in[14];
    const float* fcdw = (const float*)d_in[15];
    const float* fcdb = (const float*)d_in[16];
    const float* emb = (const float*)d_in[17];
    const float* convk = (const float*)d_in[18];
    const float* convb = (const float*)d_in[19];
    const float* fctw = (const float*)d_in[20];
    const float* fctb = (const float*)d_in[21];
    const float* cw1 = (const float*)d_in[22];
    const float* cb1 = (const float*)d_in[23];
    const float* cw2 = (const float*)d_in[24];
    const float* cb2 = (const float*)d_in[25];
    const float* cw3 = (const float*)d_in[26];
    const float* cb3 = (const float*)d_in[27];

    const int* src = ei;
    const int* dst = ei + EE;

    size_t off = 0;
    auto alloc = [&](size_t bytes) {
        size_t o = off;
        off = (off + bytes + 255) & ~(size_t)255;
        return o;
    };
    char* ws = (char*)d_ws;
    size_t o_rp = alloc(4ull * (NN + 1));
    size_t o_col = alloc(4ull * EE);
    size_t o_bc = alloc(4ull * 256);
    size_t o_bb = alloc(4ull * 256);
    size_t o_ha = alloc(2ull * NN * 32);
    size_t o_hb = alloc(2ull * NN * 32);
    size_t o_eb = alloc(8ull * NB * ESLOT);
    size_t o_part = alloc(4ull * 2048 * 64);
    size_t o_aff = alloc(4ull * 64);
    size_t o_w1f = alloc(2ull * 2048);
    size_t o_wf1 = alloc(2ull * 1024);
    size_t o_wf2 = alloc(2ull * 1024);
    size_t o_tv = alloc(4ull * 32);
    size_t o_ps = alloc(4ull * BB * 32);
    size_t o_cnt = alloc(4ull * BB);
    size_t o_xdv = alloc(4ull * BB * 128);
    size_t o_kT = alloc(4ull * LL * 256);
    size_t o_c = alloc(4ull * BB * CF);
    size_t o_xtv = alloc(4ull * BB * 128);
    size_t o_h1 = alloc(4ull * BB * 1024);
    size_t o_h2 = alloc(4ull * BB * 256);

    int* rp = (int*)(ws + o_rp);
    int* col = (int*)(ws + o_col);
    int* bcur = (int*)(ws + o_bc);
    int* bbase = (int*)(ws + o_bb);
    __half* ha = (__half*)(ws + o_ha);
    __half* hb = (__half*)(ws + o_hb);
    unsigned long long* ebuf = (unsigned long long*)(ws + o_eb);
    float* part = (float*)(ws + o_part);
    float* aff = (float*)(ws + o_aff);
    __half* w1f = (__half*)(ws + o_w1f);
    __half* wf1 = (__half*)(ws + o_wf1);
    __half* wf2 = (__half*)(ws + o_wf2);
    float* tvb = (float*)(ws + o_tv);
    float* ps = (float*)(ws + o_ps);
    int* cnt = (int*)(ws + o_cnt);
    float* xdv = (float*)(ws + o_xdv);
    float* kT = (float*)(ws + o_kT);
    float* cbuf = (float*)(ws + o_c);
    float* xtv = (float*)(ws + o_xtv);
    float* h1 = (float*)(ws + o_h1);
    float* h2 = (float*)(ws + o_h2);
    float* dout = (float*)d_out;

    // --- CSR build (bucketed two-pass) ---
    hipMemsetAsync(bcur, 0, 4ull * NB, stream);
    k_bscatter<<<977, 256, 0, stream>>>(src, dst, bcur, ebuf);
    k_bscan<<<1, 256, 0, stream>>>(bcur, bbase);
    k_build<<<NB, 256, 0, stream>>>(ebuf, bbase, bcur, rp, col);

    // --- GIN layers (fused gather + MFMA mlp) ---
    k_pfrag<<<1, 64, 0, stream>>>(g1w1, w1f);
    k_p1<<<2048, 256, 0, stream>>>(xd, w1f, ha);

    // layer 1
    k_wfrag<1><<<1, 64, 0, stream>>>(aff, g1w1, g1w2, wf1, wf2, tvb);
    k_mlp<1><<<2048, 256, 0, stream>>>(ha, rp, col, wf1, wf2, tvb, g1b1, g1b2, hb, part);
    k_reduce<<<32, 256, 0, stream>>>(part, 2048, bng, bnb, aff);

    const __half* srcbuf = hb;
    __half* dstbuf = ha;
    for (int i = 0; i < 4; ++i) {
        k_wfrag<0><<<1, 64, 0, stream>>>(aff, grw1 + (size_t)i * 1024, grw2 + (size_t)i * 1024,
                                         wf1, wf2, tvb);
        k_mlp<0><<<2048, 256, 0, stream>>>(srcbuf, rp, col, wf1, wf2, tvb,
                                           grb1 + (size_t)i * 32, grb2 + (size_t)i * 32,
                                           dstbuf, part);
        k_reduce<<<32, 256, 0, stream>>>(part, 2048, bng + (i + 1) * 32, bnb + (i + 1) * 32, aff);
        const __half* tmp = srcbuf;
        srcbuf = dstbuf;
        dstbuf = (__half*)tmp;
    }
    // after loop: srcbuf == layer-5 output, aff == layer-5 affine

    // --- pooling + xdv ---
    hipMemsetAsync(ps, 0, 4ull * BB * 32, stream);
    k_pool<<<1024, 256, 0, stream>>>(srcbuf, batch, ps);
    k_counts<<<4, 256, 0, stream>>>(batch, cnt);
    k_xdv<<<BB, 128, 0, stream>>>(ps, cnt, aff, fcdw, fcdb, xdv);

    // --- conv branch ---
    k_kT<<<LL, 256, 0, stream>>>(convk, kT);
    k_conv<<<BB, 256, 0, stream>>>(xt, kT, emb, convb, cbuf);
    k_binit<<<BB * 128 / 256, 256, 0, stream>>>(fctb, xtv, 127);
    k_xtv<<<512, 256, 0, stream>>>(cbuf, fctw, xtv);

    // --- classifier ---
    k_cls1<<<BB / 8, 1024, 0, stream>>>(xdv, xtv, cw1, cb1, h1);
    k_binit<<<BB * 256 / 256, 256, 0, stream>>>(cb2, h2, 255);
    k_cls2<<<512, 256, 0, stream>>>(h1, cw2, h2);
    k_cls3<<<256, 256, 0, stream>>>(h2, cw3, cb3, y, dout);
}

// Round 11
// 1078.478 us; speedup vs baseline: 1.0803x; 1.0803x over previous
//
#include <hip/hip_runtime.h>
#include <hip/hip_bf16.h>
#include <hip/hip_fp16.h>

#define NN 1000000
#define EE 4000000
#define BB 1024
#define DIM 32
#define FXDIM 55
#define EMBD 128
#define VOCAB 26
#define LL 1000
#define NF 32
#define KK 8
#define CF 3872   // 32*121
#define BSH 12
#define NB 245          // ceil(NN / 4096)
#define ESLOT 20480     // padded records per bucket

typedef _Float16 f16x8 __attribute__((ext_vector_type(8)));
typedef float f32x4 __attribute__((ext_vector_type(4)));

// ---------------- CSR build: bucketed two-pass (write-coalescing-friendly) ----------------
__global__ __launch_bounds__(256) void k_bscatter(const int* __restrict__ src,
                                                  const int* __restrict__ dst,
                                                  int* __restrict__ bcur,
                                                  unsigned long long* __restrict__ ebuf) {
    __shared__ unsigned long long rec[4096];
    __shared__ short bid[4096];
    __shared__ int cnt[NB], pref[NB], gb[NB];
    __shared__ int sc[256];
    int t = threadIdx.x;
    for (int i = t; i < NB; i += 256) cnt[i] = 0;
    __syncthreads();
    size_t base = (size_t)blockIdx.x * 4096;
    int b_[16], s_[16], d_[16];
#pragma unroll
    for (int j = 0; j < 16; ++j) {
        size_t e = base + (size_t)j * 256 + t;
        if (e < EE) {
            int d = dst[e];
            b_[j] = d >> BSH;
            d_[j] = d;
            s_[j] = src[e];
            atomicAdd(&cnt[b_[j]], 1);
        } else b_[j] = -1;
    }
    __syncthreads();
    int v = (t < NB) ? cnt[t] : 0;
    sc[t] = v;
    __syncthreads();
    for (int off = 1; off < 256; off <<= 1) {
        int a = (t >= off) ? sc[t - off] : 0;
        __syncthreads();
        sc[t] += a;
        __syncthreads();
    }
    if (t < NB) {
        pref[t] = sc[t] - v;
        gb[t] = (v > 0) ? atomicAdd(&bcur[t], v) : 0;
        cnt[t] = 0;
    }
    __syncthreads();
#pragma unroll
    for (int j = 0; j < 16; ++j) {
        if (b_[j] >= 0) {
            int r = atomicAdd(&cnt[b_[j]], 1);
            int p = pref[b_[j]] + r;
            rec[p] = ((unsigned long long)(unsigned)d_[j] << 32) | (unsigned)s_[j];
            bid[p] = (short)b_[j];
        }
    }
    __syncthreads();
    int total = sc[NB - 1];
    for (int p = t; p < total; p += 256) {
        int b = bid[p];
        size_t gp = (size_t)b * ESLOT + gb[b] + (p - pref[b]);
        ebuf[gp] = rec[p];
    }
}

__global__ void k_bscan(const int* __restrict__ bcnt, int* __restrict__ bbase) {
    __shared__ int sh[256];
    int t = threadIdx.x;
    int v = (t < NB) ? bcnt[t] : 0;
    sh[t] = v;
    __syncthreads();
    for (int off = 1; off < 256; off <<= 1) {
        int a = (t >= off) ? sh[t - off] : 0;
        __syncthreads();
        sh[t] += a;
        __syncthreads();
    }
    if (t < NB) bbase[t] = sh[t] - v;
}

__global__ __launch_bounds__(256) void k_build(const unsigned long long* __restrict__ ebuf,
                                               const int* __restrict__ bbase,
                                               const int* __restrict__ bcnt,
                                               int* __restrict__ rowptr,
                                               int* __restrict__ col) {
    __shared__ int cnt[4096];
    __shared__ int pref[4096];
    __shared__ int part[256];
    int b = blockIdx.x, t = threadIdx.x;
    int n0 = b << BSH;
    int nmax = min(4096, NN - n0);
    for (int i = t; i < 4096; i += 256) cnt[i] = 0;
    __syncthreads();
    int e0 = bbase[b];
    int ne = bcnt[b];
    const unsigned long long* eb = ebuf + (size_t)b * ESLOT;
    for (int e = t; e < ne; e += 256) {
        int d = (int)(eb[e] >> 32) & 4095;
        atomicAdd(&cnt[d], 1);
    }
    __syncthreads();
    int s = 0, loc[16];
    int bi = t * 16;
#pragma unroll
    for (int j = 0; j < 16; ++j) { loc[j] = s; s += cnt[bi + j]; }
    part[t] = s;
    __syncthreads();
    for (int off = 1; off < 256; off <<= 1) {
        int a = (t >= off) ? part[t - off] : 0;
        __syncthreads();
        part[t] += a;
        __syncthreads();
    }
    int pb = part[t] - s;
#pragma unroll
    for (int j = 0; j < 16; ++j) pref[bi + j] = pb + loc[j];
    __syncthreads();
    for (int i = t; i < nmax; i += 256) rowptr[n0 + i] = e0 + pref[i];
    if (b == NB - 1 && t == 0) rowptr[NN] = EE;
    __syncthreads();
    for (int e = t; e < ne; e += 256) {
        unsigned long long r = eb[e];
        int d = (int)(r >> 32) & 4095;
        int p = atomicAdd(&pref[d], 1);
        col[e0 + p] = (int)(r & 0xffffffffu);
    }
}

// ---------------- w1 fragment prep for MFMA p1 (K padded 55 -> 64) ----------------
__global__ __launch_bounds__(64) void k_pfrag(const float* __restrict__ w1,
                                              __half* __restrict__ w1f) {
    int l = threadIdx.x;
    int kbase = (l >> 4) * 8;
    int jj = l & 15;
#pragma unroll
    for (int q = 0; q < 2; ++q) {
#pragma unroll
        for (int c = 0; c < 2; ++c) {
            __half v[8];
#pragma unroll
            for (int i = 0; i < 8; ++i) {
                int k = q * 32 + kbase + i;
                int j = c * 16 + jj;
                v[i] = (k < FXDIM) ? __float2half_rn(w1[k * 32 + j]) : __half(0.f);
            }
            *(uint4*)&w1f[(size_t)((q * 2 + c) * 64 + l) * 8] = *(const uint4*)v;
        }
    }
}

// ---------------- layer-1 projection p = xd @ w1 via MFMA (exactly-once reads) ----------------
__global__ __launch_bounds__(256) void k_p1(const float* __restrict__ xd,
                                            const __half* __restrict__ w1f,
                                            __half* __restrict__ out) {
    __shared__ float zb[4][16 * 36];
    int tid = threadIdx.x;
    int l = tid & 63;
    int wid = tid >> 6;
    int rowg = l >> 4;
    int lan16 = l & 15;
    f16x8 bw00 = __builtin_bit_cast(f16x8, *(const uint4*)&w1f[(size_t)(0 * 64 + l) * 8]);
    f16x8 bw01 = __builtin_bit_cast(f16x8, *(const uint4*)&w1f[(size_t)(1 * 64 + l) * 8]);
    f16x8 bw10 = __builtin_bit_cast(f16x8, *(const uint4*)&w1f[(size_t)(2 * 64 + l) * 8]);
    f16x8 bw11 = __builtin_bit_cast(f16x8, *(const uint4*)&w1f[(size_t)(3 * 64 + l) * 8]);
    float* zw = zb[wid];
    int gw = (blockIdx.x * 256 + tid) >> 6;
    int ngw = (gridDim.x * 256) >> 6;
    for (int t = gw; t < NN / 16; t += ngw) {
        int n0 = t * 16;
        const float* row = xd + (size_t)(n0 + lan16) * FXDIM;
        f16x8 a0, a1;
#pragma unroll
        for (int i = 0; i < 8; ++i) a0[i] = (_Float16)row[rowg * 8 + i];
#pragma unroll
        for (int i = 0; i < 8; ++i) {
            int k = 32 + rowg * 8 + i;
            a1[i] = (k < FXDIM) ? (_Float16)row[k] : (_Float16)0.f;
        }
        f32x4 h0, h1;
#pragma unroll
        for (int r = 0; r < 4; ++r) { h0[r] = 0.f; h1[r] = 0.f; }
        h0 = __builtin_amdgcn_mfma_f32_16x16x32_f16(a0, bw00, h0, 0, 0, 0);
        h1 = __builtin_amdgcn_mfma_f32_16x16x32_f16(a0, bw01, h1, 0, 0, 0);
        h0 = __builtin_amdgcn_mfma_f32_16x16x32_f16(a1, bw10, h0, 0, 0, 0);
        h1 = __builtin_amdgcn_mfma_f32_16x16x32_f16(a1, bw11, h1, 0, 0, 0);
#pragma unroll
        for (int r = 0; r < 4; ++r) {
            int nd = rowg * 4 + r;
            zw[nd * 36 + lan16] = h0[r];
            zw[nd * 36 + 16 + lan16] = h1[r];
        }
        int sn = l >> 2, sc = (l & 3) * 8;
        f32x4 hv0 = *(const f32x4*)&zw[sn * 36 + sc];
        f32x4 hv1 = *(const f32x4*)&zw[sn * 36 + sc + 4];
        __half hh[8];
#pragma unroll
        for (int i = 0; i < 4; ++i) {
            hh[i] = __float2half_rn(hv0[i]);
            hh[4 + i] = __float2half_rn(hv1[i]);
        }
        *(uint4*)(out + (size_t)(n0 + sn) * 32 + sc) = *(const uint4*)hh;
    }
}

// ---------------- per-layer weight fragment prep (BN folded into W1) ----------------
template <int FIRST>
__global__ __launch_bounds__(64) void k_wfrag(const float* __restrict__ aff,
                                              const float* __restrict__ w1,
                                              const float* __restrict__ w2,
                                              __half* __restrict__ wf1,
                                              __half* __restrict__ wf2,
                                              float* __restrict__ tv) {
    int l = threadIdx.x;
    int kbase = (l >> 4) * 8;
    int jj = l & 15;
#pragma unroll
    for (int c = 0; c < 2; ++c) {
        int j = c * 16 + jj;
        __half v1[8], v2[8];
#pragma unroll
        for (int i = 0; i < 8; ++i) {
            int k = kbase + i;
            float s = FIRST ? 1.f : aff[k];
            v1[i] = __float2half_rn(s * w1[k * 32 + j]);
            v2[i] = __float2half_rn(w2[k * 32 + j]);
        }
        *(uint4*)&wf1[(size_t)(c * 64 + l) * 8] = *(const uint4*)v1;
        *(uint4*)&wf2[(size_t)(c * 64 + l) * 8] = *(const uint4*)v2;
    }
    if (!FIRST && l < 32) {
        float acc = 0.f;
        for (int k = 0; k < 32; ++k) acc += aff[32 + k] * w1[k * 32 + l];
        tv[l] = acc;
    }
}

// ---------------- fused GIN layer: gather-agg (2-chain) + MFMA MLP + BN stats ----------------
template <int FIRST>
__global__ __launch_bounds__(256) void k_mlp(const __half* __restrict__ hsrc,
                                             const int* __restrict__ rowptr,
                                             const int* __restrict__ colidx,
                                             const __half* __restrict__ wf1,
                                             const __half* __restrict__ wf2,
                                             const float* __restrict__ tv,
                                             const float* __restrict__ b1,
                                             const float* __restrict__ b2,
                                             __half* __restrict__ hdst,
                                             float* __restrict__ partial) {
    __shared__ float zb[4][16 * 36];
    __shared__ float sred[4][64];
    int tid = threadIdx.x;
    int l = tid & 63;
    int wid = tid >> 6;
    int rowg = l >> 4;
    int lan16 = l & 15;

    f16x8 bw2_0 = __builtin_bit_cast(f16x8, *(const uint4*)&wf2[(size_t)(0 * 64 + l) * 8]);
    f16x8 bw2_1 = __builtin_bit_cast(f16x8, *(const uint4*)&wf2[(size_t)(1 * 64 + l) * 8]);
    f16x8 bw1_0{}, bw1_1{};
    float tv0 = 0.f, tv1 = 0.f, b1c0 = 0.f, b1c1 = 0.f;
    float b1v[8];
    if (FIRST) {
#pragma unroll
        for (int i = 0; i < 8; ++i) b1v[i] = b1[rowg * 8 + i];
    } else {
        bw1_0 = __builtin_bit_cast(f16x8, *(const uint4*)&wf1[(size_t)(0 * 64 + l) * 8]);
        bw1_1 = __builtin_bit_cast(f16x8, *(const uint4*)&wf1[(size_t)(1 * 64 + l) * 8]);
        tv0 = tv[lan16];
        tv1 = tv[16 + lan16];
        b1c0 = b1[lan16];
        b1c1 = b1[16 + lan16];
    }
    float b2c0 = b2[lan16], b2c1 = b2[16 + lan16];
    float* zw = zb[wid];
    float ps0 = 0.f, ps1 = 0.f, pq0 = 0.f, pq1 = 0.f;
    int gw = (blockIdx.x * 256 + tid) >> 6;
    int ngw = (gridDim.x * 256) >> 6;
    for (int t = gw; t < NN / 16; t += ngw) {
        int n0 = t * 16;
        int node = n0 + lan16;
        int r0 = rowptr[node], r1 = rowptr[node + 1];
        // gather: self + neighbors, f32 accumulate, 2 chains
        uint4 su = *(const uint4*)(hsrc + (size_t)node * 32 + rowg * 8);
        f16x8 sf = __builtin_bit_cast(f16x8, su);
        float a0[8], a1[8];
#pragma unroll
        for (int i = 0; i < 8; ++i) { a0[i] = (float)sf[i]; a1[i] = 0.f; }
        int e = r0;
        for (; e + 2 <= r1; e += 2) {
            int s0 = colidx[e], s1 = colidx[e + 1];
            uint4 u0 = *(const uint4*)(hsrc + (size_t)s0 * 32 + rowg * 8);
            uint4 u1 = *(const uint4*)(hsrc + (size_t)s1 * 32 + rowg * 8);
            f16x8 f0 = __builtin_bit_cast(f16x8, u0);
            f16x8 f1 = __builtin_bit_cast(f16x8, u1);
#pragma unroll
            for (int i = 0; i < 8; ++i) { a0[i] += (float)f0[i]; a1[i] += (float)f1[i]; }
        }
        if (e < r1) {
            uint4 u0 = *(const uint4*)(hsrc + (size_t)colidx[e] * 32 + rowg * 8);
            f16x8 f0 = __builtin_bit_cast(f16x8, u0);
#pragma unroll
            for (int i = 0; i < 8; ++i) a1[i] += (float)f0[i];
        }
        f16x8 za;
        if (FIRST) {
#pragma unroll
            for (int i = 0; i < 8; ++i)
                za[i] = (_Float16)fmaxf(a0[i] + a1[i] + b1v[i], 0.f);
        } else {
            f16x8 af;
#pragma unroll
            for (int i = 0; i < 8; ++i) af[i] = (_Float16)(a0[i] + a1[i]);
            int rbase = n0 + rowg * 4;
            int4 rv = *(const int4*)&rowptr[rbase];
            int rext = rowptr[rbase + 4];
            float c0 = (float)(rv.y - rv.x + 1);
            float c1 = (float)(rv.z - rv.y + 1);
            float c2 = (float)(rv.w - rv.z + 1);
            float c3 = (float)(rext - rv.w + 1);
            f32x4 ac0, ac1;
            ac0[0] = fmaf(c0, tv0, b1c0); ac1[0] = fmaf(c0, tv1, b1c1);
            ac0[1] = fmaf(c1, tv0, b1c0); ac1[1] = fmaf(c1, tv1, b1c1);
            ac0[2] = fmaf(c2, tv0, b1c0); ac1[2] = fmaf(c2, tv1, b1c1);
            ac0[3] = fmaf(c3, tv0, b1c0); ac1[3] = fmaf(c3, tv1, b1c1);
            ac0 = __builtin_amdgcn_mfma_f32_16x16x32_f16(af, bw1_0, ac0, 0, 0, 0);
            ac1 = __builtin_amdgcn_mfma_f32_16x16x32_f16(af, bw1_1, ac1, 0, 0, 0);
#pragma unroll
            for (int r = 0; r < 4; ++r) {
                int nd = rowg * 4 + r;
                zw[nd * 36 + lan16] = fmaxf(ac0[r], 0.f);
                zw[nd * 36 + 16 + lan16] = fmaxf(ac1[r], 0.f);
            }
            f32x4 z0 = *(const f32x4*)&zw[lan16 * 36 + rowg * 8];
            f32x4 z1 = *(const f32x4*)&zw[lan16 * 36 + rowg * 8 + 4];
#pragma unroll
            for (int i = 0; i < 4; ++i) {
                za[i] = (_Float16)z0[i];
                za[4 + i] = (_Float16)z1[i];
            }
        }
        f32x4 h0, h1;
#pragma unroll
        for (int r = 0; r < 4; ++r) { h0[r] = b2c0; h1[r] = b2c1; }
        h0 = __builtin_amdgcn_mfma_f32_16x16x32_f16(za, bw2_0, h0, 0, 0, 0);
        h1 = __builtin_amdgcn_mfma_f32_16x16x32_f16(za, bw2_1, h1, 0, 0, 0);
#pragma unroll
        for (int r = 0; r < 4; ++r) {
            float v0 = fmaxf(h0[r], 0.f);
            float v1 = fmaxf(h1[r], 0.f);
            ps0 += v0; pq0 += v0 * v0;
            ps1 += v1; pq1 += v1 * v1;
            int nd = rowg * 4 + r;
            zw[nd * 36 + lan16] = v0;
            zw[nd * 36 + 16 + lan16] = v1;
        }
        int sn = l >> 2, sc = (l & 3) * 8;
        f32x4 hv0 = *(const f32x4*)&zw[sn * 36 + sc];
        f32x4 hv1 = *(const f32x4*)&zw[sn * 36 + sc + 4];
        __half hh[8];
#pragma unroll
        for (int i = 0; i < 4; ++i) {
            hh[i] = __float2half_rn(hv0[i]);
            hh[4 + i] = __float2half_rn(hv1[i]);
        }
        *(uint4*)(hdst + (size_t)(n0 + sn) * 32 + sc) = *(const uint4*)hh;
    }
    // stats reduce
    ps0 += __shfl_xor(ps0, 16, 64); ps0 += __shfl_xor(ps0, 32, 64);
    ps1 += __shfl_xor(ps1, 16, 64); ps1 += __shfl_xor(ps1, 32, 64);
    pq0 += __shfl_xor(pq0, 16, 64); pq0 += __shfl_xor(pq0, 32, 64);
    pq1 += __shfl_xor(pq1, 16, 64); pq1 += __shfl_xor(pq1, 32, 64);
    if (l < 16) {
        sred[wid][lan16] = ps0;
        sred[wid][16 + lan16] = ps1;
        sred[wid][32 + lan16] = pq0;
        sred[wid][48 + lan16] = pq1;
    }
    __syncthreads();
    if (tid < 64) {
        float s = sred[0][tid] + sred[1][tid] + sred[2][tid] + sred[3][tid];
        partial[(size_t)blockIdx.x * 64 + tid] = s;
    }
}

// ---------------- finalize BN stats -> affine s,t (1 block/channel) ----------------
__global__ __launch_bounds__(256) void k_reduce(const float* __restrict__ partial, int nblocks,
                                                const float* __restrict__ g, const float* __restrict__ bt,
                                                float* __restrict__ aff) {
    int c = blockIdx.x;
    int t = threadIdx.x;
    double s = 0.0, q = 0.0;
    for (int b = t; b < nblocks; b += 256) {
        s += (double)partial[(size_t)b * 64 + c];
        q += (double)partial[(size_t)b * 64 + 32 + c];
    }
    __shared__ double shs[256], shq[256];
    shs[t] = s; shq[t] = q;
    __syncthreads();
    for (int off = 128; off; off >>= 1) {
        if (t < off) { shs[t] += shs[t + off]; shq[t] += shq[t + off]; }
        __syncthreads();
    }
    if (t == 0) {
        double mean = shs[0] / (double)NN;
        double var = shq[0] / (double)NN - mean * mean;
        float r = (float)rsqrt(var + 1e-5);
        float sv = g[c] * r;
        aff[c] = sv;
        aff[32 + c] = bt[c] - (float)mean * sv;
    }
}

// ---------------- pooling (xd_batch sorted -> run-length + atomics) ----------------
__global__ __launch_bounds__(256) void k_pool(const __half* __restrict__ h,
                                              const int* __restrict__ batch,
                                              float* __restrict__ ps) {
    int lane = threadIdx.x & 31;
    int g = threadIdx.x >> 5;
    const int chunk = (NN + gridDim.x - 1) / gridDim.x;
    int s0 = blockIdx.x * chunk;
    int s1 = min(NN, s0 + chunk);
    int curb = -1;
    float acc = 0.f;
    for (int i = s0 + g; i < s1; i += 8) {
        int b = batch[i];
        if (b != curb) {
            if (curb >= 0) atomicAdd(&ps[curb * 32 + lane], acc);
            acc = 0.f;
            curb = b;
        }
        acc += __half2float(h[(size_t)i * 32 + lane]);
    }
    if (curb >= 0) atomicAdd(&ps[curb * 32 + lane], acc);
}

__device__ int lowerb(const int* a, int n, int key) {
    int lo = 0, hi = n;
    while (lo < hi) {
        int m = (lo + hi) >> 1;
        if (a[m] < key) lo = m + 1;
        else hi = m;
    }
    return lo;
}

__global__ void k_counts(const int* __restrict__ batch, int* __restrict__ cnt) {
    int b = blockIdx.x * blockDim.x + threadIdx.x;
    if (b < BB) cnt[b] = lowerb(batch, NN, b + 1) - lowerb(batch, NN, b);
}

// ---------------- xdv = ReLU(pooled' @ fcd_w + fcd_b) ----------------
__global__ __launch_bounds__(128) void k_xdv(const float* __restrict__ ps,
                                             const int* __restrict__ cnt,
                                             const float* __restrict__ aff,
                                             const float* __restrict__ w,
                                             const float* __restrict__ bb,
                                             float* __restrict__ xdv) {
    int b = blockIdx.x;
    int j = threadIdx.x;
    __shared__ float p[32];
    if (j < 32) p[j] = aff[j] * ps[b * 32 + j] + (float)cnt[b] * aff[32 + j];
    __syncthreads();
    float acc = bb[j];
#pragma unroll
    for (int c = 0; c < 32; ++c) acc += p[c] * w[c * 128 + j];
    xdv[b * 128 + j] = fmaxf(acc, 0.f);
}

// ---------------- conv branch ----------------
__global__ void k_kT(const float* __restrict__ ck, float* __restrict__ kT) {
    int i = blockIdx.x;
    int t = threadIdx.x;
    int o = t >> 3, k = t & 7;
    kT[(size_t)i * 256 + t] = ck[(size_t)o * (LL * KK) + (size_t)i * KK + k];
}

// Bucket-sorted phase 1 with 8-deep load batching (8 independent kT loads in flight).
__global__ __launch_bounds__(256) void k_conv(const int* __restrict__ xt,
                                              const float* __restrict__ kT,
                                              const float* __restrict__ emb,
                                              const float* __restrict__ cb,
                                              float* __restrict__ cbuf) {
    __shared__ float S[VOCAB * 256];        // 26.6 KB
    __shared__ unsigned short order[LL];    // 2 KB
    __shared__ int scnt[VOCAB], soff[VOCAB + 1], bcur2[VOCAB];
    int t = threadIdx.x;
    int b = blockIdx.x;
    if (t < VOCAB) { scnt[t] = 0; bcur2[t] = 0; }
    __syncthreads();
    const int* row = xt + (size_t)b * LL;
    int vi[4];
#pragma unroll
    for (int j = 0; j < 4; ++j) {
        int i = t * 4 + j;
        if (i < LL) {
            vi[j] = row[i];
            atomicAdd(&scnt[vi[j]], 1);
        } else vi[j] = -1;
    }
    __syncthreads();
    if (t == 0) {
        int run = 0;
#pragma unroll
        for (int v = 0; v < VOCAB; ++v) { soff[v] = run; run += scnt[v]; }
        soff[VOCAB] = LL;
    }
    __syncthreads();
#pragma unroll
    for (int j = 0; j < 4; ++j) {
        if (vi[j] >= 0) {
            int pos = atomicAdd(&bcur2[vi[j]], 1);
            order[soff[vi[j]] + pos] = (unsigned short)(t * 4 + j);
        }
    }
    __syncthreads();
    // phase 1: S[v][t] = sum over bucket_v of kT[i*256+t]; 8 loads in flight per iter
    for (int v = 0; v < VOCAB; ++v) {
        int e0 = soff[v], e1 = soff[v + 1];
        float s0 = 0.f, s1 = 0.f, s2 = 0.f, s3 = 0.f;
        float s4 = 0.f, s5 = 0.f, s6 = 0.f, s7 = 0.f;
        int e = e0;
        for (; e + 8 <= e1; e += 8) {
            int i0 = order[e], i1 = order[e + 1], i2 = order[e + 2], i3 = order[e + 3];
            int i4 = order[e + 4], i5 = order[e + 5], i6 = order[e + 6], i7 = order[e + 7];
            float v0 = kT[(size_t)i0 * 256 + t];
            float v1 = kT[(size_t)i1 * 256 + t];
            float v2 = kT[(size_t)i2 * 256 + t];
            float v3 = kT[(size_t)i3 * 256 + t];
            float v4 = kT[(size_t)i4 * 256 + t];
            float v5 = kT[(size_t)i5 * 256 + t];
            float v6 = kT[(size_t)i6 * 256 + t];
            float v7 = kT[(size_t)i7 * 256 + t];
            s0 += v0; s1 += v1; s2 += v2; s3 += v3;
            s4 += v4; s5 += v5; s6 += v6; s7 += v7;
        }
        if (e + 4 <= e1) {
            int i0 = order[e], i1 = order[e + 1], i2 = order[e + 2], i3 = order[e + 3];
            float v0 = kT[(size_t)i0 * 256 + t];
            float v1 = kT[(size_t)i1 * 256 + t];
            float v2 = kT[(size_t)i2 * 256 + t];
            float v3 = kT[(size_t)i3 * 256 + t];
            s4 += v0; s5 += v1; s6 += v2; s7 += v3;
            e += 4;
        }
        if (e + 2 <= e1) {
            int i0 = order[e], i1 = order[e + 1];
            s1 += kT[(size_t)i0 * 256 + t];
            s2 += kT[(size_t)i1 * 256 + t];
            e += 2;
        }
        if (e < e1) s0 += kT[(size_t)order[e] * 256 + t];
        S[v * 256 + t] = ((s0 + s1) + (s2 + s3)) + ((s4 + s5) + (s6 + s7));
    }
    __syncthreads();
    // phase 2: out[o,h] = cb[o] + sum_v sum_k S[v,o,k] * emb[v,h+k]
    int h = t & 127, half = t >> 7;
    if (h < 121) {
        float acc[16];
        int o0 = half * 16;
#pragma unroll
        for (int o = 0; o < 16; ++o) acc[o] = cb[o0 + o];
        for (int v = 0; v < VOCAB; ++v) {
            float e[8];
#pragma unroll
            for (int k = 0; k < 8; ++k) e[k] = emb[v * EMBD + h + k];   // L1-resident
#pragma unroll
            for (int o = 0; o < 16; ++o) {
                float a = acc[o];
#pragma unroll
                for (int k = 0; k < 8; ++k) a += S[v * 256 + (o0 + o) * 8 + k] * e[k];
                acc[o] = a;
            }
        }
#pragma unroll
        for (int o = 0; o < 16; ++o)
            cbuf[(size_t)b * CF + (size_t)(o0 + o) * 121 + h] = acc[o];
    }
}

// ---------------- bias init ----------------
__global__ void k_binit(const float* __restrict__ bias, float* __restrict__ out, int mask) {
    int i = blockIdx.x * blockDim.x + threadIdx.x;
    out[i] = bias[i & mask];
}

// ---------------- xtv += c_tile @ w_tile (split-K, LDS-tiled, atomic accumulate) ----------------
__global__ __launch_bounds__(256) void k_xtv(const float* __restrict__ c,
                                             const float* __restrict__ w,
                                             float* __restrict__ xtv) {
    __shared__ float ct[16][484];
    int rb = blockIdx.x >> 3, kc = blockIdx.x & 7;
    int b0 = rb * 16, k0 = kc * 484;
    int tid = threadIdx.x;
#pragma unroll
    for (int r = 0; r < 16; ++r)
        for (int k = tid; k < 484; k += 256)
            ct[r][k] = c[(size_t)(b0 + r) * CF + k0 + k];
    __syncthreads();
    int j = tid & 127, rh = tid >> 7;
    float acc[8];
#pragma unroll
    for (int r = 0; r < 8; ++r) acc[r] = 0.f;
    const float2* ct2 = (const float2*)&ct[0][0];
    for (int k2 = 0; k2 < 242; ++k2) {
        float w0 = w[(size_t)(k0 + 2 * k2) * 128 + j];
        float w1 = w[(size_t)(k0 + 2 * k2 + 1) * 128 + j];
#pragma unroll
        for (int r = 0; r < 8; ++r) {
            float2 cv = ct2[(rh * 8 + r) * 242 + k2];
            acc[r] = fmaf(cv.x, w0, fmaf(cv.y, w1, acc[r]));
        }
    }
#pragma unroll
    for (int r = 0; r < 8; ++r)
        atomicAdd(&xtv[(size_t)(b0 + rh * 8 + r) * 128 + j], acc[r]);
}

// ---------------- classifier ----------------
__global__ __launch_bounds__(1024) void k_cls1(const float* __restrict__ xdv,
                                               const float* __restrict__ xtv,
                                               const float* __restrict__ w,
                                               const float* __restrict__ bb,
                                               float* __restrict__ h1) {
    __shared__ float X[8][256];
    int j = threadIdx.x;
    int b0 = blockIdx.x * 8;
    for (int idx = j; idx < 8 * 256; idx += 1024) {
        int r = idx >> 8, k = idx & 255;
        X[r][k] = (k < 128) ? xdv[(b0 + r) * 128 + k] : xtv[(b0 + r) * 128 + (k - 128)];
    }
    __syncthreads();
    float acc[8];
#pragma unroll
    for (int r = 0; r < 8; ++r) acc[r] = bb[j];
    for (int k = 0; k < 256; ++k) {
        float wv = w[(size_t)k * 1024 + j];
#pragma unroll
        for (int r = 0; r < 8; ++r) acc[r] += X[r][k] * wv;
    }
#pragma unroll
    for (int r = 0; r < 8; ++r) h1[(size_t)(b0 + r) * 1024 + j] = fmaxf(acc[r], 0.f);
}

__global__ __launch_bounds__(256) void k_cls2(const float* __restrict__ h1,
                                              const float* __restrict__ w,
                                              float* __restrict__ h2) {
    __shared__ float X[8][256];
    int rb = blockIdx.x >> 2, kc = blockIdx.x & 3;
    int b0 = rb * 8, k0 = kc * 256;
    int tid = threadIdx.x;
#pragma unroll
    for (int r = 0; r < 8; ++r)
        X[r][tid] = h1[(size_t)(b0 + r) * 1024 + k0 + tid];
    __syncthreads();
    int j = tid;
    float acc[8];
#pragma unroll
    for (int r = 0; r < 8; ++r) acc[r] = 0.f;
    const float2* X2 = (const float2*)&X[0][0];
    for (int k2 = 0; k2 < 128; ++k2) {
        float w0 = w[(size_t)(k0 + 2 * k2) * 256 + j];
        float w1 = w[(size_t)(k0 + 2 * k2 + 1) * 256 + j];
#pragma unroll
        for (int r = 0; r < 8; ++r) {
            float2 xv = X2[r * 128 + k2];
            acc[r] = fmaf(xv.x, w0, fmaf(xv.y, w1, acc[r]));
        }
    }
#pragma unroll
    for (int r = 0; r < 8; ++r)
        atomicAdd(&h2[(size_t)(b0 + r) * 256 + j], acc[r]);
}

__global__ __launch_bounds__(256) void k_cls3(const float* __restrict__ h2,
                                              const float* __restrict__ w,
                                              const float* __restrict__ bb,
                                              const float* __restrict__ y,
                                              float* __restrict__ dout) {
    int lane = threadIdx.x & 63;
    int b = (blockIdx.x * blockDim.x + threadIdx.x) >> 6;
    if (b >= BB) return;
    float acc = 0.f;
    for (int k = lane; k < 256; k += 64) acc += fmaxf(h2[(size_t)b * 256 + k], 0.f) * w[k];
#pragma unroll
    for (int off = 32; off; off >>= 1) acc += __shfl_xor(acc, off, 64);
    if (lane == 0) dout[b] = acc + bb[0];
    if (lane == 1) dout[BB + b] = y[b];
}

// ---------------- launch ----------------
extern "C" void kernel_launch(void* const* d_in, const int* in_sizes, int n_in,
                              void* d_out, int out_size, void* d_ws, size_t ws_size,
                              hipStream_t stream) {
    const float* xd = (const float*)d_in[0];
    const int* ei = (const int*)d_in[1];
    const int* batch = (const int*)d_in[2];
    const int* xt = (const int*)d_in[3];
    const float* y = (const float*)d_in[4];
    const float* g1w1 = (const float*)d_in[5];
    const float* g1b1 = (const float*)d_in[6];
    const float* g1w2 = (const float*)d_in[7];
    const float* g1b2 = (const float*)d_in[8];
    const float* grw1 = (const float*)d_in[9];
    const float* grb1 = (const float*)d_in[10];
    const float* grw2 = (const float*)d_in[11];
    const float* grb2 = (const float*)d_in[12];
    const float* bng = (const float*)d_in[13];
    const float* bnb = (const float*)d_in[14];
    const float* fcdw = (const float*)d_in[15];
    const float* fcdb = (const float*)d_in[16];
    const float* emb = (const float*)d_in[17];
    const float* convk = (const float*)d_in[18];
    const float* convb = (const float*)d_in[19];
    const float* fctw = (const float*)d_in[20];
    const float* fctb = (const float*)d_in[21];
    const float* cw1 = (const float*)d_in[22];
    const float* cb1 = (const float*)d_in[23];
    const float* cw2 = (const float*)d_in[24];
    const float* cb2 = (const float*)d_in[25];
    const float* cw3 = (const float*)d_in[26];
    const float* cb3 = (const float*)d_in[27];

    const int* src = ei;
    const int* dst = ei + EE;

    size_t off = 0;
    auto alloc = [&](size_t bytes) {
        size_t o = off;
        off = (off + bytes + 255) & ~(size_t)255;
        return o;
    };
    char* ws = (char*)d_ws;
    size_t o_rp = alloc(4ull * (NN + 1));
    size_t o_col = alloc(4ull * EE);
    size_t o_bc = alloc(4ull * 256);
    size_t o_bb = alloc(4ull * 256);
    size_t o_ha = alloc(2ull * NN * 32);
    size_t o_hb = alloc(2ull * NN * 32);
    size_t o_eb = alloc(8ull * NB * ESLOT);
    size_t o_part = alloc(4ull * 2048 * 64);
    size_t o_aff = alloc(4ull * 64);
    size_t o_w1f = alloc(2ull * 2048);
    size_t o_wf1 = alloc(2ull * 1024);
    size_t o_wf2 = alloc(2ull * 1024);
    size_t o_tv = alloc(4ull * 32);
    size_t o_ps = alloc(4ull * BB * 32);
    size_t o_cnt = alloc(4ull * BB);
    size_t o_xdv = alloc(4ull * BB * 128);
    size_t o_kT = alloc(4ull * LL * 256);
    size_t o_c = alloc(4ull * BB * CF);
    size_t o_xtv = alloc(4ull * BB * 128);
    size_t o_h1 = alloc(4ull * BB * 1024);
    size_t o_h2 = alloc(4ull * BB * 256);

    int* rp = (int*)(ws + o_rp);
    int* col = (int*)(ws + o_col);
    int* bcur = (int*)(ws + o_bc);
    int* bbase = (int*)(ws + o_bb);
    __half* ha = (__half*)(ws + o_ha);
    __half* hb = (__half*)(ws + o_hb);
    unsigned long long* ebuf = (unsigned long long*)(ws + o_eb);
    float* part = (float*)(ws + o_part);
    float* aff = (float*)(ws + o_aff);
    __half* w1f = (__half*)(ws + o_w1f);
    __half* wf1 = (__half*)(ws + o_wf1);
    __half* wf2 = (__half*)(ws + o_wf2);
    float* tvb = (float*)(ws + o_tv);
    float* ps = (float*)(ws + o_ps);
    int* cnt = (int*)(ws + o_cnt);
    float* xdv = (float*)(ws + o_xdv);
    float* kT = (float*)(ws + o_kT);
    float* cbuf = (float*)(ws + o_c);
    float* xtv = (float*)(ws + o_xtv);
    float* h1 = (float*)(ws + o_h1);
    float* h2 = (float*)(ws + o_h2);
    float* dout = (float*)d_out;

    // --- CSR build (bucketed two-pass) ---
    hipMemsetAsync(bcur, 0, 4ull * NB, stream);
    k_bscatter<<<977, 256, 0, stream>>>(src, dst, bcur, ebuf);
    k_bscan<<<1, 256, 0, stream>>>(bcur, bbase);
    k_build<<<NB, 256, 0, stream>>>(ebuf, bbase, bcur, rp, col);

    // --- GIN layers (fused gather + MFMA mlp) ---
    k_pfrag<<<1, 64, 0, stream>>>(g1w1, w1f);
    k_p1<<<2048, 256, 0, stream>>>(xd, w1f, ha);

    // layer 1
    k_wfrag<1><<<1, 64, 0, stream>>>(aff, g1w1, g1w2, wf1, wf2, tvb);
    k_mlp<1><<<2048, 256, 0, stream>>>(ha, rp, col, wf1, wf2, tvb, g1b1, g1b2, hb, part);
    k_reduce<<<32, 256, 0, stream>>>(part, 2048, bng, bnb, aff);

    const __half* srcbuf = hb;
    __half* dstbuf = ha;
    for (int i = 0; i < 4; ++i) {
        k_wfrag<0><<<1, 64, 0, stream>>>(aff, grw1 + (size_t)i * 1024, grw2 + (size_t)i * 1024,
                                         wf1, wf2, tvb);
        k_mlp<0><<<2048, 256, 0, stream>>>(srcbuf, rp, col, wf1, wf2, tvb,
                                           grb1 + (size_t)i * 32, grb2 + (size_t)i * 32,
                                           dstbuf, part);
        k_reduce<<<32, 256, 0, stream>>>(part, 2048, bng + (i + 1) * 32, bnb + (i + 1) * 32, aff);
        const __half* tmp = srcbuf;
        srcbuf = dstbuf;
        dstbuf = (__half*)tmp;
    }
    // after loop: srcbuf == layer-5 output, aff == layer-5 affine

    // --- pooling + xdv ---
    hipMemsetAsync(ps, 0, 4ull * BB * 32, stream);
    k_pool<<<1024, 256, 0, stream>>>(srcbuf, batch, ps);
    k_counts<<<4, 256, 0, stream>>>(batch, cnt);
    k_xdv<<<BB, 128, 0, stream>>>(ps, cnt, aff, fcdw, fcdb, xdv);

    // --- conv branch ---
    k_kT<<<LL, 256, 0, stream>>>(convk, kT);
    k_conv<<<BB, 256, 0, stream>>>(xt, kT, emb, convb, cbuf);
    k_binit<<<BB * 128 / 256, 256, 0, stream>>>(fctb, xtv, 127);
    k_xtv<<<512, 256, 0, stream>>>(cbuf, fctw, xtv);

    // --- classifier ---
    k_cls1<<<BB / 8, 1024, 0, stream>>>(xdv, xtv, cw1, cb1, h1);
    k_binit<<<BB * 256 / 256, 256, 0, stream>>>(cb2, h2, 255);
    k_cls2<<<512, 256, 0, stream>>>(h1, cw2, h2);
    k_cls3<<<256, 256, 0, stream>>>(h2, cw3, cb3, y, dout);
}

// Round 12
// 1075.002 us; speedup vs baseline: 1.0838x; 1.0032x over previous
//
#include <hip/hip_runtime.h>
#include <hip/hip_bf16.h>
#include <hip/hip_fp16.h>

#define NN 1000000
#define EE 4000000
#define BB 1024
#define DIM 32
#define FXDIM 55
#define EMBD 128
#define VOCAB 26
#define LL 1000
#define NF 32
#define KK 8
#define CF 3872   // 32*121
#define BSH 12
#define NB 245          // ceil(NN / 4096)
#define ESLOT 20480     // padded records per bucket

typedef _Float16 f16x8 __attribute__((ext_vector_type(8)));
typedef float f32x4 __attribute__((ext_vector_type(4)));

// ---------------- CSR build: bucketed two-pass (write-coalescing-friendly) ----------------
__global__ __launch_bounds__(256) void k_bscatter(const int* __restrict__ src,
                                                  const int* __restrict__ dst,
                                                  int* __restrict__ bcur,
                                                  unsigned long long* __restrict__ ebuf) {
    __shared__ unsigned long long rec[4096];
    __shared__ short bid[4096];
    __shared__ int cnt[NB], pref[NB], gb[NB];
    __shared__ int sc[256];
    int t = threadIdx.x;
    for (int i = t; i < NB; i += 256) cnt[i] = 0;
    __syncthreads();
    size_t base = (size_t)blockIdx.x * 4096;
    int b_[16], s_[16], d_[16];
#pragma unroll
    for (int j = 0; j < 16; ++j) {
        size_t e = base + (size_t)j * 256 + t;
        if (e < EE) {
            int d = dst[e];
            b_[j] = d >> BSH;
            d_[j] = d;
            s_[j] = src[e];
            atomicAdd(&cnt[b_[j]], 1);
        } else b_[j] = -1;
    }
    __syncthreads();
    int v = (t < NB) ? cnt[t] : 0;
    sc[t] = v;
    __syncthreads();
    for (int off = 1; off < 256; off <<= 1) {
        int a = (t >= off) ? sc[t - off] : 0;
        __syncthreads();
        sc[t] += a;
        __syncthreads();
    }
    if (t < NB) {
        pref[t] = sc[t] - v;
        gb[t] = (v > 0) ? atomicAdd(&bcur[t], v) : 0;
        cnt[t] = 0;
    }
    __syncthreads();
#pragma unroll
    for (int j = 0; j < 16; ++j) {
        if (b_[j] >= 0) {
            int r = atomicAdd(&cnt[b_[j]], 1);
            int p = pref[b_[j]] + r;
            rec[p] = ((unsigned long long)(unsigned)d_[j] << 32) | (unsigned)s_[j];
            bid[p] = (short)b_[j];
        }
    }
    __syncthreads();
    int total = sc[NB - 1];
    for (int p = t; p < total; p += 256) {
        int b = bid[p];
        size_t gp = (size_t)b * ESLOT + gb[b] + (p - pref[b]);
        ebuf[gp] = rec[p];
    }
}

__global__ void k_bscan(const int* __restrict__ bcnt, int* __restrict__ bbase) {
    __shared__ int sh[256];
    int t = threadIdx.x;
    int v = (t < NB) ? bcnt[t] : 0;
    sh[t] = v;
    __syncthreads();
    for (int off = 1; off < 256; off <<= 1) {
        int a = (t >= off) ? sh[t - off] : 0;
        __syncthreads();
        sh[t] += a;
        __syncthreads();
    }
    if (t < NB) bbase[t] = sh[t] - v;
}

__global__ __launch_bounds__(256) void k_build(const unsigned long long* __restrict__ ebuf,
                                               const int* __restrict__ bbase,
                                               const int* __restrict__ bcnt,
                                               int* __restrict__ rowptr,
                                               int* __restrict__ col) {
    __shared__ int cnt[4096];
    __shared__ int pref[4096];
    __shared__ int part[256];
    int b = blockIdx.x, t = threadIdx.x;
    int n0 = b << BSH;
    int nmax = min(4096, NN - n0);
    for (int i = t; i < 4096; i += 256) cnt[i] = 0;
    __syncthreads();
    int e0 = bbase[b];
    int ne = bcnt[b];
    const unsigned long long* eb = ebuf + (size_t)b * ESLOT;
    for (int e = t; e < ne; e += 256) {
        int d = (int)(eb[e] >> 32) & 4095;
        atomicAdd(&cnt[d], 1);
    }
    __syncthreads();
    int s = 0, loc[16];
    int bi = t * 16;
#pragma unroll
    for (int j = 0; j < 16; ++j) { loc[j] = s; s += cnt[bi + j]; }
    part[t] = s;
    __syncthreads();
    for (int off = 1; off < 256; off <<= 1) {
        int a = (t >= off) ? part[t - off] : 0;
        __syncthreads();
        part[t] += a;
        __syncthreads();
    }
    int pb = part[t] - s;
#pragma unroll
    for (int j = 0; j < 16; ++j) pref[bi + j] = pb + loc[j];
    __syncthreads();
    for (int i = t; i < nmax; i += 256) rowptr[n0 + i] = e0 + pref[i];
    if (b == NB - 1 && t == 0) rowptr[NN] = EE;
    __syncthreads();
    for (int e = t; e < ne; e += 256) {
        unsigned long long r = eb[e];
        int d = (int)(r >> 32) & 4095;
        int p = atomicAdd(&pref[d], 1);
        col[e0 + p] = (int)(r & 0xffffffffu);
    }
}

// ---------------- w1 fragment prep for MFMA p1 (K padded 55 -> 64) ----------------
__global__ __launch_bounds__(64) void k_pfrag(const float* __restrict__ w1,
                                              __half* __restrict__ w1f) {
    int l = threadIdx.x;
    int kbase = (l >> 4) * 8;
    int jj = l & 15;
#pragma unroll
    for (int q = 0; q < 2; ++q) {
#pragma unroll
        for (int c = 0; c < 2; ++c) {
            __half v[8];
#pragma unroll
            for (int i = 0; i < 8; ++i) {
                int k = q * 32 + kbase + i;
                int j = c * 16 + jj;
                v[i] = (k < FXDIM) ? __float2half_rn(w1[k * 32 + j]) : __half(0.f);
            }
            *(uint4*)&w1f[(size_t)((q * 2 + c) * 64 + l) * 8] = *(const uint4*)v;
        }
    }
}

// ---------------- layer-1 projection p = xd @ w1 via MFMA (exactly-once reads) ----------------
__global__ __launch_bounds__(256) void k_p1(const float* __restrict__ xd,
                                            const __half* __restrict__ w1f,
                                            __half* __restrict__ out) {
    __shared__ float zb[4][16 * 36];
    int tid = threadIdx.x;
    int l = tid & 63;
    int wid = tid >> 6;
    int rowg = l >> 4;
    int lan16 = l & 15;
    f16x8 bw00 = __builtin_bit_cast(f16x8, *(const uint4*)&w1f[(size_t)(0 * 64 + l) * 8]);
    f16x8 bw01 = __builtin_bit_cast(f16x8, *(const uint4*)&w1f[(size_t)(1 * 64 + l) * 8]);
    f16x8 bw10 = __builtin_bit_cast(f16x8, *(const uint4*)&w1f[(size_t)(2 * 64 + l) * 8]);
    f16x8 bw11 = __builtin_bit_cast(f16x8, *(const uint4*)&w1f[(size_t)(3 * 64 + l) * 8]);
    float* zw = zb[wid];
    int gw = (blockIdx.x * 256 + tid) >> 6;
    int ngw = (gridDim.x * 256) >> 6;
    for (int t = gw; t < NN / 16; t += ngw) {
        int n0 = t * 16;
        const float* row = xd + (size_t)(n0 + lan16) * FXDIM;
        f16x8 a0, a1;
#pragma unroll
        for (int i = 0; i < 8; ++i) a0[i] = (_Float16)row[rowg * 8 + i];
#pragma unroll
        for (int i = 0; i < 8; ++i) {
            int k = 32 + rowg * 8 + i;
            a1[i] = (k < FXDIM) ? (_Float16)row[k] : (_Float16)0.f;
        }
        f32x4 h0, h1;
#pragma unroll
        for (int r = 0; r < 4; ++r) { h0[r] = 0.f; h1[r] = 0.f; }
        h0 = __builtin_amdgcn_mfma_f32_16x16x32_f16(a0, bw00, h0, 0, 0, 0);
        h1 = __builtin_amdgcn_mfma_f32_16x16x32_f16(a0, bw01, h1, 0, 0, 0);
        h0 = __builtin_amdgcn_mfma_f32_16x16x32_f16(a1, bw10, h0, 0, 0, 0);
        h1 = __builtin_amdgcn_mfma_f32_16x16x32_f16(a1, bw11, h1, 0, 0, 0);
#pragma unroll
        for (int r = 0; r < 4; ++r) {
            int nd = rowg * 4 + r;
            zw[nd * 36 + lan16] = h0[r];
            zw[nd * 36 + 16 + lan16] = h1[r];
        }
        int sn = l >> 2, sc = (l & 3) * 8;
        f32x4 hv0 = *(const f32x4*)&zw[sn * 36 + sc];
        f32x4 hv1 = *(const f32x4*)&zw[sn * 36 + sc + 4];
        __half hh[8];
#pragma unroll
        for (int i = 0; i < 4; ++i) {
            hh[i] = __float2half_rn(hv0[i]);
            hh[4 + i] = __float2half_rn(hv1[i]);
        }
        *(uint4*)(out + (size_t)(n0 + sn) * 32 + sc) = *(const uint4*)hh;
    }
}

// ---------------- per-layer weight fragment prep (BN folded into W1) ----------------
// wf1: A-frag of W1'^T (also valid B-frag layout — same per-lane data).
// wf2: A-frag of W2^T with hidden-channel permutation sigma folded in (non-FIRST):
//   sigma(rowg*8+i) = rowg*4+i (i<4) | 16+rowg*4+(i-4) (i>=4); identity for FIRST.
template <int FIRST>
__global__ __launch_bounds__(64) void k_wfrag(const float* __restrict__ aff,
                                              const float* __restrict__ w1,
                                              const float* __restrict__ w2,
                                              __half* __restrict__ wf1,
                                              __half* __restrict__ wf2,
                                              float* __restrict__ tv) {
    int l = threadIdx.x;
    int rowg = l >> 4;
    int jj = l & 15;
#pragma unroll
    for (int c = 0; c < 2; ++c) {
        int j = c * 16 + jj;
        __half v1[8], v2[8];
#pragma unroll
        for (int i = 0; i < 8; ++i) {
            int k = rowg * 8 + i;
            float s = FIRST ? 1.f : aff[k];
            v1[i] = __float2half_rn(s * w1[k * 32 + j]);
            int p = FIRST ? k : ((i < 4) ? (rowg * 4 + i) : (16 + rowg * 4 + (i - 4)));
            v2[i] = __float2half_rn(w2[p * 32 + j]);
        }
        *(uint4*)&wf1[(size_t)(c * 64 + l) * 8] = *(const uint4*)v1;
        *(uint4*)&wf2[(size_t)(c * 64 + l) * 8] = *(const uint4*)v2;
    }
    if (!FIRST && l < 32) {
        float acc = 0.f;
        for (int k = 0; k < 32; ++k) acc += aff[32 + k] * w1[k * 32 + l];
        tv[l] = acc;
    }
}

// ---------------- fused GIN layer: gather-agg + swapped-operand MFMA MLP (no LDS transposes) ----------------
// Computes Z^T = W1'^T @ agg^T and H^T = W2'^T @ Z^T: gathered rows ARE the B-frag,
// GEMM1's D feeds GEMM2's B-frag directly (hidden channels permuted via wf2 packing).
template <int FIRST>
__global__ __launch_bounds__(256) void k_mlp(const __half* __restrict__ hsrc,
                                             const int* __restrict__ rowptr,
                                             const int* __restrict__ colidx,
                                             const __half* __restrict__ wf1,
                                             const __half* __restrict__ wf2,
                                             const float* __restrict__ tv,
                                             const float* __restrict__ b1,
                                             const float* __restrict__ b2,
                                             __half* __restrict__ hdst,
                                             float* __restrict__ partial) {
    __shared__ float sred[4][64];
    int tid = threadIdx.x;
    int l = tid & 63;
    int wid = tid >> 6;
    int rowg = l >> 4;
    int lan16 = l & 15;

    f16x8 wA2_0 = __builtin_bit_cast(f16x8, *(const uint4*)&wf2[(size_t)(0 * 64 + l) * 8]);
    f16x8 wA2_1 = __builtin_bit_cast(f16x8, *(const uint4*)&wf2[(size_t)(1 * 64 + l) * 8]);
    f16x8 wA1_0{}, wA1_1{};
    float b1v[8];
    float b1a[4], b1b[4], tva[4], tvb_[4];
    if (FIRST) {
#pragma unroll
        for (int i = 0; i < 8; ++i) b1v[i] = b1[rowg * 8 + i];
    } else {
        wA1_0 = __builtin_bit_cast(f16x8, *(const uint4*)&wf1[(size_t)(0 * 64 + l) * 8]);
        wA1_1 = __builtin_bit_cast(f16x8, *(const uint4*)&wf1[(size_t)(1 * 64 + l) * 8]);
#pragma unroll
        for (int r = 0; r < 4; ++r) {
            b1a[r] = b1[rowg * 4 + r];
            b1b[r] = b1[16 + rowg * 4 + r];
            tva[r] = tv[rowg * 4 + r];
            tvb_[r] = tv[16 + rowg * 4 + r];
        }
    }
    float b2a[4], b2b[4];
#pragma unroll
    for (int r = 0; r < 4; ++r) {
        b2a[r] = b2[rowg * 4 + r];
        b2b[r] = b2[16 + rowg * 4 + r];
    }
    float sa[4] = {0.f, 0.f, 0.f, 0.f}, sb[4] = {0.f, 0.f, 0.f, 0.f};
    float qa[4] = {0.f, 0.f, 0.f, 0.f}, qb[4] = {0.f, 0.f, 0.f, 0.f};

    int gw = (blockIdx.x * 256 + tid) >> 6;
    int ngw = (gridDim.x * 256) >> 6;
    for (int t = gw; t < NN / 16; t += ngw) {
        int n0 = t * 16;
        int node = n0 + lan16;
        int r0 = rowptr[node], r1 = rowptr[node + 1];
        // gather: self + neighbors, f32 accumulate, 2 chains
        uint4 su = *(const uint4*)(hsrc + (size_t)node * 32 + rowg * 8);
        f16x8 sf = __builtin_bit_cast(f16x8, su);
        float a0[8], a1[8];
#pragma unroll
        for (int i = 0; i < 8; ++i) { a0[i] = (float)sf[i]; a1[i] = 0.f; }
        int e = r0;
        for (; e + 2 <= r1; e += 2) {
            int s0 = colidx[e], s1 = colidx[e + 1];
            uint4 u0 = *(const uint4*)(hsrc + (size_t)s0 * 32 + rowg * 8);
            uint4 u1 = *(const uint4*)(hsrc + (size_t)s1 * 32 + rowg * 8);
            f16x8 f0 = __builtin_bit_cast(f16x8, u0);
            f16x8 f1 = __builtin_bit_cast(f16x8, u1);
#pragma unroll
            for (int i = 0; i < 8; ++i) { a0[i] += (float)f0[i]; a1[i] += (float)f1[i]; }
        }
        if (e < r1) {
            uint4 u0 = *(const uint4*)(hsrc + (size_t)colidx[e] * 32 + rowg * 8);
            f16x8 f0 = __builtin_bit_cast(f16x8, u0);
#pragma unroll
            for (int i = 0; i < 8; ++i) a1[i] += (float)f0[i];
        }
        f16x8 frag;   // B-frag of Z^T (slot i -> physical hidden sigma(rowg*8+i))
        if (FIRST) {
#pragma unroll
            for (int i = 0; i < 8; ++i)
                frag[i] = (_Float16)fmaxf(a0[i] + a1[i] + b1v[i], 0.f);
        } else {
            f16x8 af;   // B-frag of agg^T
#pragma unroll
            for (int i = 0; i < 8; ++i) af[i] = (_Float16)(a0[i] + a1[i]);
            float cf = (float)(r1 - r0 + 1);
            f32x4 ca, cb;
#pragma unroll
            for (int r = 0; r < 4; ++r) {
                ca[r] = fmaf(cf, tva[r], b1a[r]);
                cb[r] = fmaf(cf, tvb_[r], b1b[r]);
            }
            ca = __builtin_amdgcn_mfma_f32_16x16x32_f16(wA1_0, af, ca, 0, 0, 0);
            cb = __builtin_amdgcn_mfma_f32_16x16x32_f16(wA1_1, af, cb, 0, 0, 0);
#pragma unroll
            for (int i = 0; i < 4; ++i) {
                frag[i] = (_Float16)fmaxf(ca[i], 0.f);
                frag[4 + i] = (_Float16)fmaxf(cb[i], 0.f);
            }
        }
        f32x4 ha, hb;
#pragma unroll
        for (int r = 0; r < 4; ++r) { ha[r] = b2a[r]; hb[r] = b2b[r]; }
        ha = __builtin_amdgcn_mfma_f32_16x16x32_f16(wA2_0, frag, ha, 0, 0, 0);
        hb = __builtin_amdgcn_mfma_f32_16x16x32_f16(wA2_1, frag, hb, 0, 0, 0);
        __half oa[4], ob[4];
#pragma unroll
        for (int r = 0; r < 4; ++r) {
            float va = fmaxf(ha[r], 0.f);
            float vb = fmaxf(hb[r], 0.f);
            sa[r] += va; qa[r] += va * va;
            sb[r] += vb; qb[r] += vb * vb;
            oa[r] = __float2half_rn(va);
            ob[r] = __float2half_rn(vb);
        }
        *(uint2*)(hdst + (size_t)node * 32 + rowg * 4) = *(const uint2*)oa;
        *(uint2*)(hdst + (size_t)node * 32 + 16 + rowg * 4) = *(const uint2*)ob;
    }
    // stats: reduce across the 16-lane node dimension (once per kernel)
#pragma unroll
    for (int r = 0; r < 4; ++r) {
#pragma unroll
        for (int off = 1; off < 16; off <<= 1) {
            sa[r] += __shfl_xor(sa[r], off, 64);
            sb[r] += __shfl_xor(sb[r], off, 64);
            qa[r] += __shfl_xor(qa[r], off, 64);
            qb[r] += __shfl_xor(qb[r], off, 64);
        }
    }
    if (lan16 == 0) {
#pragma unroll
        for (int r = 0; r < 4; ++r) {
            sred[wid][rowg * 4 + r] = sa[r];
            sred[wid][16 + rowg * 4 + r] = sb[r];
            sred[wid][32 + rowg * 4 + r] = qa[r];
            sred[wid][48 + rowg * 4 + r] = qb[r];
        }
    }
    __syncthreads();
    if (tid < 64) {
        float s = sred[0][tid] + sred[1][tid] + sred[2][tid] + sred[3][tid];
        partial[(size_t)blockIdx.x * 64 + tid] = s;
    }
}

// ---------------- finalize BN stats -> affine s,t (1 block/channel) ----------------
__global__ __launch_bounds__(256) void k_reduce(const float* __restrict__ partial, int nblocks,
                                                const float* __restrict__ g, const float* __restrict__ bt,
                                                float* __restrict__ aff) {
    int c = blockIdx.x;
    int t = threadIdx.x;
    double s = 0.0, q = 0.0;
    for (int b = t; b < nblocks; b += 256) {
        s += (double)partial[(size_t)b * 64 + c];
        q += (double)partial[(size_t)b * 64 + 32 + c];
    }
    __shared__ double shs[256], shq[256];
    shs[t] = s; shq[t] = q;
    __syncthreads();
    for (int off = 128; off; off >>= 1) {
        if (t < off) { shs[t] += shs[t + off]; shq[t] += shq[t + off]; }
        __syncthreads();
    }
    if (t == 0) {
        double mean = shs[0] / (double)NN;
        double var = shq[0] / (double)NN - mean * mean;
        float r = (float)rsqrt(var + 1e-5);
        float sv = g[c] * r;
        aff[c] = sv;
        aff[32 + c] = bt[c] - (float)mean * sv;
    }
}

// ---------------- pooling (xd_batch sorted -> run-length + atomics) ----------------
__global__ __launch_bounds__(256) void k_pool(const __half* __restrict__ h,
                                              const int* __restrict__ batch,
                                              float* __restrict__ ps) {
    int lane = threadIdx.x & 31;
    int g = threadIdx.x >> 5;
    const int chunk = (NN + gridDim.x - 1) / gridDim.x;
    int s0 = blockIdx.x * chunk;
    int s1 = min(NN, s0 + chunk);
    int curb = -1;
    float acc = 0.f;
    for (int i = s0 + g; i < s1; i += 8) {
        int b = batch[i];
        if (b != curb) {
            if (curb >= 0) atomicAdd(&ps[curb * 32 + lane], acc);
            acc = 0.f;
            curb = b;
        }
        acc += __half2float(h[(size_t)i * 32 + lane]);
    }
    if (curb >= 0) atomicAdd(&ps[curb * 32 + lane], acc);
}

__device__ int lowerb(const int* a, int n, int key) {
    int lo = 0, hi = n;
    while (lo < hi) {
        int m = (lo + hi) >> 1;
        if (a[m] < key) lo = m + 1;
        else hi = m;
    }
    return lo;
}

__global__ void k_counts(const int* __restrict__ batch, int* __restrict__ cnt) {
    int b = blockIdx.x * blockDim.x + threadIdx.x;
    if (b < BB) cnt[b] = lowerb(batch, NN, b + 1) - lowerb(batch, NN, b);
}

// ---------------- xdv = ReLU(pooled' @ fcd_w + fcd_b) ----------------
__global__ __launch_bounds__(128) void k_xdv(const float* __restrict__ ps,
                                             const int* __restrict__ cnt,
                                             const float* __restrict__ aff,
                                             const float* __restrict__ w,
                                             const float* __restrict__ bb,
                                             float* __restrict__ xdv) {
    int b = blockIdx.x;
    int j = threadIdx.x;
    __shared__ float p[32];
    if (j < 32) p[j] = aff[j] * ps[b * 32 + j] + (float)cnt[b] * aff[32 + j];
    __syncthreads();
    float acc = bb[j];
#pragma unroll
    for (int c = 0; c < 32; ++c) acc += p[c] * w[c * 128 + j];
    xdv[b * 128 + j] = fmaxf(acc, 0.f);
}

// ---------------- conv branch ----------------
__global__ void k_kT(const float* __restrict__ ck, float* __restrict__ kT) {
    int i = blockIdx.x;
    int t = threadIdx.x;
    int o = t >> 3, k = t & 7;
    kT[(size_t)i * 256 + t] = ck[(size_t)o * (LL * KK) + (size_t)i * KK + k];
}

// Bucket-sorted phase 1 with 8-deep load batching (8 independent kT loads in flight).
__global__ __launch_bounds__(256) void k_conv(const int* __restrict__ xt,
                                              const float* __restrict__ kT,
                                              const float* __restrict__ emb,
                                              const float* __restrict__ cb,
                                              float* __restrict__ cbuf) {
    __shared__ float S[VOCAB * 256];        // 26.6 KB
    __shared__ unsigned short order[LL];    // 2 KB
    __shared__ int scnt[VOCAB], soff[VOCAB + 1], bcur2[VOCAB];
    int t = threadIdx.x;
    int b = blockIdx.x;
    if (t < VOCAB) { scnt[t] = 0; bcur2[t] = 0; }
    __syncthreads();
    const int* row = xt + (size_t)b * LL;
    int vi[4];
#pragma unroll
    for (int j = 0; j < 4; ++j) {
        int i = t * 4 + j;
        if (i < LL) {
            vi[j] = row[i];
            atomicAdd(&scnt[vi[j]], 1);
        } else vi[j] = -1;
    }
    __syncthreads();
    if (t == 0) {
        int run = 0;
#pragma unroll
        for (int v = 0; v < VOCAB; ++v) { soff[v] = run; run += scnt[v]; }
        soff[VOCAB] = LL;
    }
    __syncthreads();
#pragma unroll
    for (int j = 0; j < 4; ++j) {
        if (vi[j] >= 0) {
            int pos = atomicAdd(&bcur2[vi[j]], 1);
            order[soff[vi[j]] + pos] = (unsigned short)(t * 4 + j);
        }
    }
    __syncthreads();
    // phase 1: S[v][t] = sum over bucket_v of kT[i*256+t]; 8 loads in flight per iter
    for (int v = 0; v < VOCAB; ++v) {
        int e0 = soff[v], e1 = soff[v + 1];
        float s0 = 0.f, s1 = 0.f, s2 = 0.f, s3 = 0.f;
        float s4 = 0.f, s5 = 0.f, s6 = 0.f, s7 = 0.f;
        int e = e0;
        for (; e + 8 <= e1; e += 8) {
            int i0 = order[e], i1 = order[e + 1], i2 = order[e + 2], i3 = order[e + 3];
            int i4 = order[e + 4], i5 = order[e + 5], i6 = order[e + 6], i7 = order[e + 7];
            float v0 = kT[(size_t)i0 * 256 + t];
            float v1 = kT[(size_t)i1 * 256 + t];
            float v2 = kT[(size_t)i2 * 256 + t];
            float v3 = kT[(size_t)i3 * 256 + t];
            float v4 = kT[(size_t)i4 * 256 + t];
            float v5 = kT[(size_t)i5 * 256 + t];
            float v6 = kT[(size_t)i6 * 256 + t];
            float v7 = kT[(size_t)i7 * 256 + t];
            s0 += v0; s1 += v1; s2 += v2; s3 += v3;
            s4 += v4; s5 += v5; s6 += v6; s7 += v7;
        }
        if (e + 4 <= e1) {
            int i0 = order[e], i1 = order[e + 1], i2 = order[e + 2], i3 = order[e + 3];
            float v0 = kT[(size_t)i0 * 256 + t];
            float v1 = kT[(size_t)i1 * 256 + t];
            float v2 = kT[(size_t)i2 * 256 + t];
            float v3 = kT[(size_t)i3 * 256 + t];
            s4 += v0; s5 += v1; s6 += v2; s7 += v3;
            e += 4;
        }
        if (e + 2 <= e1) {
            int i0 = order[e], i1 = order[e + 1];
            s1 += kT[(size_t)i0 * 256 + t];
            s2 += kT[(size_t)i1 * 256 + t];
            e += 2;
        }
        if (e < e1) s0 += kT[(size_t)order[e] * 256 + t];
        S[v * 256 + t] = ((s0 + s1) + (s2 + s3)) + ((s4 + s5) + (s6 + s7));
    }
    __syncthreads();
    // phase 2: out[o,h] = cb[o] + sum_v sum_k S[v,o,k] * emb[v,h+k]
    int h = t & 127, half = t >> 7;
    if (h < 121) {
        float acc[16];
        int o0 = half * 16;
#pragma unroll
        for (int o = 0; o < 16; ++o) acc[o] = cb[o0 + o];
        for (int v = 0; v < VOCAB; ++v) {
            float e[8];
#pragma unroll
            for (int k = 0; k < 8; ++k) e[k] = emb[v * EMBD + h + k];   // L1-resident
#pragma unroll
            for (int o = 0; o < 16; ++o) {
                float a = acc[o];
#pragma unroll
                for (int k = 0; k < 8; ++k) a += S[v * 256 + (o0 + o) * 8 + k] * e[k];
                acc[o] = a;
            }
        }
#pragma unroll
        for (int o = 0; o < 16; ++o)
            cbuf[(size_t)b * CF + (size_t)(o0 + o) * 121 + h] = acc[o];
    }
}

// ---------------- bias init ----------------
__global__ void k_binit(const float* __restrict__ bias, float* __restrict__ out, int mask) {
    int i = blockIdx.x * blockDim.x + threadIdx.x;
    out[i] = bias[i & mask];
}

// ---------------- xtv += c_tile @ w_tile (split-K, LDS-tiled, atomic accumulate) ----------------
__global__ __launch_bounds__(256) void k_xtv(const float* __restrict__ c,
                                             const float* __restrict__ w,
                                             float* __restrict__ xtv) {
    __shared__ float ct[16][484];
    int rb = blockIdx.x >> 3, kc = blockIdx.x & 7;
    int b0 = rb * 16, k0 = kc * 484;
    int tid = threadIdx.x;
#pragma unroll
    for (int r = 0; r < 16; ++r)
        for (int k = tid; k < 484; k += 256)
            ct[r][k] = c[(size_t)(b0 + r) * CF + k0 + k];
    __syncthreads();
    int j = tid & 127, rh = tid >> 7;
    float acc[8];
#pragma unroll
    for (int r = 0; r < 8; ++r) acc[r] = 0.f;
    const float2* ct2 = (const float2*)&ct[0][0];
    for (int k2 = 0; k2 < 242; ++k2) {
        float w0 = w[(size_t)(k0 + 2 * k2) * 128 + j];
        float w1 = w[(size_t)(k0 + 2 * k2 + 1) * 128 + j];
#pragma unroll
        for (int r = 0; r < 8; ++r) {
            float2 cv = ct2[(rh * 8 + r) * 242 + k2];
            acc[r] = fmaf(cv.x, w0, fmaf(cv.y, w1, acc[r]));
        }
    }
#pragma unroll
    for (int r = 0; r < 8; ++r)
        atomicAdd(&xtv[(size_t)(b0 + rh * 8 + r) * 128 + j], acc[r]);
}

// ---------------- classifier ----------------
__global__ __launch_bounds__(1024) void k_cls1(const float* __restrict__ xdv,
                                               const float* __restrict__ xtv,
                                               const float* __restrict__ w,
                                               const float* __restrict__ bb,
                                               float* __restrict__ h1) {
    __shared__ float X[8][256];
    int j = threadIdx.x;
    int b0 = blockIdx.x * 8;
    for (int idx = j; idx < 8 * 256; idx += 1024) {
        int r = idx >> 8, k = idx & 255;
        X[r][k] = (k < 128) ? xdv[(b0 + r) * 128 + k] : xtv[(b0 + r) * 128 + (k - 128)];
    }
    __syncthreads();
    float acc[8];
#pragma unroll
    for (int r = 0; r < 8; ++r) acc[r] = bb[j];
    for (int k = 0; k < 256; ++k) {
        float wv = w[(size_t)k * 1024 + j];
#pragma unroll
        for (int r = 0; r < 8; ++r) acc[r] += X[r][k] * wv;
    }
#pragma unroll
    for (int r = 0; r < 8; ++r) h1[(size_t)(b0 + r) * 1024 + j] = fmaxf(acc[r], 0.f);
}

__global__ __launch_bounds__(256) void k_cls2(const float* __restrict__ h1,
                                              const float* __restrict__ w,
                                              float* __restrict__ h2) {
    __shared__ float X[8][256];
    int rb = blockIdx.x >> 2, kc = blockIdx.x & 3;
    int b0 = rb * 8, k0 = kc * 256;
    int tid = threadIdx.x;
#pragma unroll
    for (int r = 0; r < 8; ++r)
        X[r][tid] = h1[(size_t)(b0 + r) * 1024 + k0 + tid];
    __syncthreads();
    int j = tid;
    float acc[8];
#pragma unroll
    for (int r = 0; r < 8; ++r) acc[r] = 0.f;
    const float2* X2 = (const float2*)&X[0][0];
    for (int k2 = 0; k2 < 128; ++k2) {
        float w0 = w[(size_t)(k0 + 2 * k2) * 256 + j];
        float w1 = w[(size_t)(k0 + 2 * k2 + 1) * 256 + j];
#pragma unroll
        for (int r = 0; r < 8; ++r) {
            float2 xv = X2[r * 128 + k2];
            acc[r] = fmaf(xv.x, w0, fmaf(xv.y, w1, acc[r]));
        }
    }
#pragma unroll
    for (int r = 0; r < 8; ++r)
        atomicAdd(&h2[(size_t)(b0 + r) * 256 + j], acc[r]);
}

__global__ __launch_bounds__(256) void k_cls3(const float* __restrict__ h2,
                                              const float* __restrict__ w,
                                              const float* __restrict__ bb,
                                              const float* __restrict__ y,
                                              float* __restrict__ dout) {
    int lane = threadIdx.x & 63;
    int b = (blockIdx.x * blockDim.x + threadIdx.x) >> 6;
    if (b >= BB) return;
    float acc = 0.f;
    for (int k = lane; k < 256; k += 64) acc += fmaxf(h2[(size_t)b * 256 + k], 0.f) * w[k];
#pragma unroll
    for (int off = 32; off; off >>= 1) acc += __shfl_xor(acc, off, 64);
    if (lane == 0) dout[b] = acc + bb[0];
    if (lane == 1) dout[BB + b] = y[b];
}

// ---------------- launch ----------------
extern "C" void kernel_launch(void* const* d_in, const int* in_sizes, int n_in,
                              void* d_out, int out_size, void* d_ws, size_t ws_size,
                              hipStream_t stream) {
    const float* xd = (const float*)d_in[0];
    const int* ei = (const int*)d_in[1];
    const int* batch = (const int*)d_in[2];
    const int* xt = (const int*)d_in[3];
    const float* y = (const float*)d_in[4];
    const float* g1w1 = (const float*)d_in[5];
    const float* g1b1 = (const float*)d_in[6];
    const float* g1w2 = (const float*)d_in[7];
    const float* g1b2 = (const float*)d_in[8];
    const float* grw1 = (const float*)d_in[9];
    const float* grb1 = (const float*)d_in[10];
    const float* grw2 = (const float*)d_in[11];
    const float* grb2 = (const float*)d_in[12];
    const float* bng = (const float*)d_in[13];
    const float* bnb = (const float*)d_in[14];
    const float* fcdw = (const float*)d_in[15];
    const float* fcdb = (const float*)d_in[16];
    const float* emb = (const float*)d_in[17];
    const float* convk = (const float*)d_in[18];
    const float* convb = (const float*)d_in[19];
    const float* fctw = (const float*)d_in[20];
    const float* fctb = (const float*)d_in[21];
    const float* cw1 = (const float*)d_in[22];
    const float* cb1 = (const float*)d_in[23];
    const float* cw2 = (const float*)d_in[24];
    const float* cb2 = (const float*)d_in[25];
    const float* cw3 = (const float*)d_in[26];
    const float* cb3 = (const float*)d_in[27];

    const int* src = ei;
    const int* dst = ei + EE;

    size_t off = 0;
    auto alloc = [&](size_t bytes) {
        size_t o = off;
        off = (off + bytes + 255) & ~(size_t)255;
        return o;
    };
    char* ws = (char*)d_ws;
    size_t o_rp = alloc(4ull * (NN + 1));
    size_t o_col = alloc(4ull * EE);
    size_t o_bc = alloc(4ull * 256);
    size_t o_bb = alloc(4ull * 256);
    size_t o_ha = alloc(2ull * NN * 32);
    size_t o_hb = alloc(2ull * NN * 32);
    size_t o_eb = alloc(8ull * NB * ESLOT);
    size_t o_part = alloc(4ull * 2048 * 64);
    size_t o_aff = alloc(4ull * 64);
    size_t o_w1f = alloc(2ull * 2048);
    size_t o_wf1 = alloc(2ull * 1024);
    size_t o_wf2 = alloc(2ull * 1024);
    size_t o_tv = alloc(4ull * 32);
    size_t o_ps = alloc(4ull * BB * 32);
    size_t o_cnt = alloc(4ull * BB);
    size_t o_xdv = alloc(4ull * BB * 128);
    size_t o_kT = alloc(4ull * LL * 256);
    size_t o_c = alloc(4ull * BB * CF);
    size_t o_xtv = alloc(4ull * BB * 128);
    size_t o_h1 = alloc(4ull * BB * 1024);
    size_t o_h2 = alloc(4ull * BB * 256);

    int* rp = (int*)(ws + o_rp);
    int* col = (int*)(ws + o_col);
    int* bcur = (int*)(ws + o_bc);
    int* bbase = (int*)(ws + o_bb);
    __half* ha = (__half*)(ws + o_ha);
    __half* hb = (__half*)(ws + o_hb);
    unsigned long long* ebuf = (unsigned long long*)(ws + o_eb);
    float* part = (float*)(ws + o_part);
    float* aff = (float*)(ws + o_aff);
    __half* w1f = (__half*)(ws + o_w1f);
    __half* wf1 = (__half*)(ws + o_wf1);
    __half* wf2 = (__half*)(ws + o_wf2);
    float* tvb = (float*)(ws + o_tv);
    float* ps = (float*)(ws + o_ps);
    int* cnt = (int*)(ws + o_cnt);
    float* xdv = (float*)(ws + o_xdv);
    float* kT = (float*)(ws + o_kT);
    float* cbuf = (float*)(ws + o_c);
    float* xtv = (float*)(ws + o_xtv);
    float* h1 = (float*)(ws + o_h1);
    float* h2 = (float*)(ws + o_h2);
    float* dout = (float*)d_out;

    // --- CSR build (bucketed two-pass) ---
    hipMemsetAsync(bcur, 0, 4ull * NB, stream);
    k_bscatter<<<977, 256, 0, stream>>>(src, dst, bcur, ebuf);
    k_bscan<<<1, 256, 0, stream>>>(bcur, bbase);
    k_build<<<NB, 256, 0, stream>>>(ebuf, bbase, bcur, rp, col);

    // --- GIN layers (fused gather + swapped MFMA mlp) ---
    k_pfrag<<<1, 64, 0, stream>>>(g1w1, w1f);
    k_p1<<<2048, 256, 0, stream>>>(xd, w1f, ha);

    // layer 1
    k_wfrag<1><<<1, 64, 0, stream>>>(aff, g1w1, g1w2, wf1, wf2, tvb);
    k_mlp<1><<<2048, 256, 0, stream>>>(ha, rp, col, wf1, wf2, tvb, g1b1, g1b2, hb, part);
    k_reduce<<<32, 256, 0, stream>>>(part, 2048, bng, bnb, aff);

    const __half* srcbuf = hb;
    __half* dstbuf = ha;
    for (int i = 0; i < 4; ++i) {
        k_wfrag<0><<<1, 64, 0, stream>>>(aff, grw1 + (size_t)i * 1024, grw2 + (size_t)i * 1024,
                                         wf1, wf2, tvb);
        k_mlp<0><<<2048, 256, 0, stream>>>(srcbuf, rp, col, wf1, wf2, tvb,
                                           grb1 + (size_t)i * 32, grb2 + (size_t)i * 32,
                                           dstbuf, part);
        k_reduce<<<32, 256, 0, stream>>>(part, 2048, bng + (i + 1) * 32, bnb + (i + 1) * 32, aff);
        const __half* tmp = srcbuf;
        srcbuf = dstbuf;
        dstbuf = (__half*)tmp;
    }
    // after loop: srcbuf == layer-5 output, aff == layer-5 affine

    // --- pooling + xdv ---
    hipMemsetAsync(ps, 0, 4ull * BB * 32, stream);
    k_pool<<<1024, 256, 0, stream>>>(srcbuf, batch, ps);
    k_counts<<<4, 256, 0, stream>>>(batch, cnt);
    k_xdv<<<BB, 128, 0, stream>>>(ps, cnt, aff, fcdw, fcdb, xdv);

    // --- conv branch ---
    k_kT<<<LL, 256, 0, stream>>>(convk, kT);
    k_conv<<<BB, 256, 0, stream>>>(xt, kT, emb, convb, cbuf);
    k_binit<<<BB * 128 / 256, 256, 0, stream>>>(fctb, xtv, 127);
    k_xtv<<<512, 256, 0, stream>>>(cbuf, fctw, xtv);

    // --- classifier ---
    k_cls1<<<BB / 8, 1024, 0, stream>>>(xdv, xtv, cw1, cb1, h1);
    k_binit<<<BB * 256 / 256, 256, 0, stream>>>(cb2, h2, 255);
    k_cls2<<<512, 256, 0, stream>>>(h1, cw2, h2);
    k_cls3<<<256, 256, 0, stream>>>(h2, cw3, cb3, y, dout);
}

// Round 13
// 1051.324 us; speedup vs baseline: 1.1082x; 1.0225x over previous
//
#include <hip/hip_runtime.h>
#include <hip/hip_bf16.h>
#include <hip/hip_fp16.h>

#define NN 1000000
#define EE 4000000
#define BB 1024
#define DIM 32
#define FXDIM 55
#define EMBD 128
#define VOCAB 26
#define LL 1000
#define NF 32
#define KK 8
#define CF 3872   // 32*121
#define BSH 12
#define NB 245          // ceil(NN / 4096)
#define ESLOT 20480     // padded records per bucket

typedef _Float16 f16x8 __attribute__((ext_vector_type(8)));
typedef float f32x4 __attribute__((ext_vector_type(4)));

// ---------------- CSR build: bucketed two-pass (write-coalescing-friendly) ----------------
__global__ __launch_bounds__(256) void k_bscatter(const int* __restrict__ src,
                                                  const int* __restrict__ dst,
                                                  int* __restrict__ bcur,
                                                  unsigned long long* __restrict__ ebuf) {
    __shared__ unsigned long long rec[4096];
    __shared__ short bid[4096];
    __shared__ int cnt[NB], pref[NB], gb[NB];
    __shared__ int sc[256];
    int t = threadIdx.x;
    for (int i = t; i < NB; i += 256) cnt[i] = 0;
    __syncthreads();
    size_t base = (size_t)blockIdx.x * 4096;
    int b_[16], s_[16], d_[16];
#pragma unroll
    for (int j = 0; j < 16; ++j) {
        size_t e = base + (size_t)j * 256 + t;
        if (e < EE) {
            int d = dst[e];
            b_[j] = d >> BSH;
            d_[j] = d;
            s_[j] = src[e];
            atomicAdd(&cnt[b_[j]], 1);
        } else b_[j] = -1;
    }
    __syncthreads();
    int v = (t < NB) ? cnt[t] : 0;
    sc[t] = v;
    __syncthreads();
    for (int off = 1; off < 256; off <<= 1) {
        int a = (t >= off) ? sc[t - off] : 0;
        __syncthreads();
        sc[t] += a;
        __syncthreads();
    }
    if (t < NB) {
        pref[t] = sc[t] - v;
        gb[t] = (v > 0) ? atomicAdd(&bcur[t], v) : 0;
        cnt[t] = 0;
    }
    __syncthreads();
#pragma unroll
    for (int j = 0; j < 16; ++j) {
        if (b_[j] >= 0) {
            int r = atomicAdd(&cnt[b_[j]], 1);
            int p = pref[b_[j]] + r;
            rec[p] = ((unsigned long long)(unsigned)d_[j] << 32) | (unsigned)s_[j];
            bid[p] = (short)b_[j];
        }
    }
    __syncthreads();
    int total = sc[NB - 1];
    for (int p = t; p < total; p += 256) {
        int b = bid[p];
        size_t gp = (size_t)b * ESLOT + gb[b] + (p - pref[b]);
        ebuf[gp] = rec[p];
    }
}

__global__ void k_bscan(const int* __restrict__ bcnt, int* __restrict__ bbase) {
    __shared__ int sh[256];
    int t = threadIdx.x;
    int v = (t < NB) ? bcnt[t] : 0;
    sh[t] = v;
    __syncthreads();
    for (int off = 1; off < 256; off <<= 1) {
        int a = (t >= off) ? sh[t - off] : 0;
        __syncthreads();
        sh[t] += a;
        __syncthreads();
    }
    if (t < NB) bbase[t] = sh[t] - v;
}

__global__ __launch_bounds__(256) void k_build(const unsigned long long* __restrict__ ebuf,
                                               const int* __restrict__ bbase,
                                               const int* __restrict__ bcnt,
                                               int* __restrict__ rowptr,
                                               int* __restrict__ col) {
    __shared__ int cnt[4096];
    __shared__ int pref[4096];
    __shared__ int part[256];
    int b = blockIdx.x, t = threadIdx.x;
    int n0 = b << BSH;
    int nmax = min(4096, NN - n0);
    for (int i = t; i < 4096; i += 256) cnt[i] = 0;
    __syncthreads();
    int e0 = bbase[b];
    int ne = bcnt[b];
    const unsigned long long* eb = ebuf + (size_t)b * ESLOT;
    for (int e = t; e < ne; e += 256) {
        int d = (int)(eb[e] >> 32) & 4095;
        atomicAdd(&cnt[d], 1);
    }
    __syncthreads();
    int s = 0, loc[16];
    int bi = t * 16;
#pragma unroll
    for (int j = 0; j < 16; ++j) { loc[j] = s; s += cnt[bi + j]; }
    part[t] = s;
    __syncthreads();
    for (int off = 1; off < 256; off <<= 1) {
        int a = (t >= off) ? part[t - off] : 0;
        __syncthreads();
        part[t] += a;
        __syncthreads();
    }
    int pb = part[t] - s;
#pragma unroll
    for (int j = 0; j < 16; ++j) pref[bi + j] = pb + loc[j];
    __syncthreads();
    for (int i = t; i < nmax; i += 256) rowptr[n0 + i] = e0 + pref[i];
    if (b == NB - 1 && t == 0) rowptr[NN] = EE;
    __syncthreads();
    for (int e = t; e < ne; e += 256) {
        unsigned long long r = eb[e];
        int d = (int)(r >> 32) & 4095;
        int p = atomicAdd(&pref[d], 1);
        col[e0 + p] = (int)(r & 0xffffffffu);
    }
}

// ---------------- w1 fragment prep for MFMA p1 (K padded 55 -> 64) ----------------
__global__ __launch_bounds__(64) void k_pfrag(const float* __restrict__ w1,
                                              __half* __restrict__ w1f) {
    int l = threadIdx.x;
    int kbase = (l >> 4) * 8;
    int jj = l & 15;
#pragma unroll
    for (int q = 0; q < 2; ++q) {
#pragma unroll
        for (int c = 0; c < 2; ++c) {
            __half v[8];
#pragma unroll
            for (int i = 0; i < 8; ++i) {
                int k = q * 32 + kbase + i;
                int j = c * 16 + jj;
                v[i] = (k < FXDIM) ? __float2half_rn(w1[k * 32 + j]) : __half(0.f);
            }
            *(uint4*)&w1f[(size_t)((q * 2 + c) * 64 + l) * 8] = *(const uint4*)v;
        }
    }
}

// ---------------- layer-1 projection p = xd @ w1 via MFMA (exactly-once reads) ----------------
__global__ __launch_bounds__(256) void k_p1(const float* __restrict__ xd,
                                            const __half* __restrict__ w1f,
                                            __half* __restrict__ out) {
    __shared__ float zb[4][16 * 36];
    int tid = threadIdx.x;
    int l = tid & 63;
    int wid = tid >> 6;
    int rowg = l >> 4;
    int lan16 = l & 15;
    f16x8 bw00 = __builtin_bit_cast(f16x8, *(const uint4*)&w1f[(size_t)(0 * 64 + l) * 8]);
    f16x8 bw01 = __builtin_bit_cast(f16x8, *(const uint4*)&w1f[(size_t)(1 * 64 + l) * 8]);
    f16x8 bw10 = __builtin_bit_cast(f16x8, *(const uint4*)&w1f[(size_t)(2 * 64 + l) * 8]);
    f16x8 bw11 = __builtin_bit_cast(f16x8, *(const uint4*)&w1f[(size_t)(3 * 64 + l) * 8]);
    float* zw = zb[wid];
    int gw = (blockIdx.x * 256 + tid) >> 6;
    int ngw = (gridDim.x * 256) >> 6;
    for (int t = gw; t < NN / 16; t += ngw) {
        int n0 = t * 16;
        const float* row = xd + (size_t)(n0 + lan16) * FXDIM;
        f16x8 a0, a1;
#pragma unroll
        for (int i = 0; i < 8; ++i) a0[i] = (_Float16)row[rowg * 8 + i];
#pragma unroll
        for (int i = 0; i < 8; ++i) {
            int k = 32 + rowg * 8 + i;
            a1[i] = (k < FXDIM) ? (_Float16)row[k] : (_Float16)0.f;
        }
        f32x4 h0, h1;
#pragma unroll
        for (int r = 0; r < 4; ++r) { h0[r] = 0.f; h1[r] = 0.f; }
        h0 = __builtin_amdgcn_mfma_f32_16x16x32_f16(a0, bw00, h0, 0, 0, 0);
        h1 = __builtin_amdgcn_mfma_f32_16x16x32_f16(a0, bw01, h1, 0, 0, 0);
        h0 = __builtin_amdgcn_mfma_f32_16x16x32_f16(a1, bw10, h0, 0, 0, 0);
        h1 = __builtin_amdgcn_mfma_f32_16x16x32_f16(a1, bw11, h1, 0, 0, 0);
#pragma unroll
        for (int r = 0; r < 4; ++r) {
            int nd = rowg * 4 + r;
            zw[nd * 36 + lan16] = h0[r];
            zw[nd * 36 + 16 + lan16] = h1[r];
        }
        int sn = l >> 2, sc = (l & 3) * 8;
        f32x4 hv0 = *(const f32x4*)&zw[sn * 36 + sc];
        f32x4 hv1 = *(const f32x4*)&zw[sn * 36 + sc + 4];
        __half hh[8];
#pragma unroll
        for (int i = 0; i < 4; ++i) {
            hh[i] = __float2half_rn(hv0[i]);
            hh[4 + i] = __float2half_rn(hv1[i]);
        }
        *(uint4*)(out + (size_t)(n0 + sn) * 32 + sc) = *(const uint4*)hh;
    }
}

// ---------------- per-layer weight fragment prep (BN folded into W1) ----------------
// wf1: A-frag of W1'^T; wf2: A-frag of W2^T with hidden-channel permutation sigma
// folded in (non-FIRST): sigma(rowg*8+i) = rowg*4+i (i<4) | 16+rowg*4+(i-4) (i>=4).
template <int FIRST>
__global__ __launch_bounds__(64) void k_wfrag(const float* __restrict__ aff,
                                              const float* __restrict__ w1,
                                              const float* __restrict__ w2,
                                              __half* __restrict__ wf1,
                                              __half* __restrict__ wf2,
                                              float* __restrict__ tv) {
    int l = threadIdx.x;
    int rowg = l >> 4;
    int jj = l & 15;
#pragma unroll
    for (int c = 0; c < 2; ++c) {
        int j = c * 16 + jj;
        __half v1[8], v2[8];
#pragma unroll
        for (int i = 0; i < 8; ++i) {
            int k = rowg * 8 + i;
            float s = FIRST ? 1.f : aff[k];
            v1[i] = __float2half_rn(s * w1[k * 32 + j]);
            int p = FIRST ? k : ((i < 4) ? (rowg * 4 + i) : (16 + rowg * 4 + (i - 4)));
            v2[i] = __float2half_rn(w2[p * 32 + j]);
        }
        *(uint4*)&wf1[(size_t)(c * 64 + l) * 8] = *(const uint4*)v1;
        *(uint4*)&wf2[(size_t)(c * 64 + l) * 8] = *(const uint4*)v2;
    }
    if (!FIRST && l < 32) {
        float acc = 0.f;
        for (int k = 0; k < 32; ++k) acc += aff[32 + k] * w1[k * 32 + l];
        tv[l] = acc;
    }
}

// ---------------- fused GIN layer: f16 packed-add gather (4 chains) + swapped MFMA MLP ----------------
template <int FIRST>
__global__ __launch_bounds__(256) void k_mlp(const __half* __restrict__ hsrc,
                                             const int* __restrict__ rowptr,
                                             const int* __restrict__ colidx,
                                             const __half* __restrict__ wf1,
                                             const __half* __restrict__ wf2,
                                             const float* __restrict__ tv,
                                             const float* __restrict__ b1,
                                             const float* __restrict__ b2,
                                             __half* __restrict__ hdst,
                                             float* __restrict__ partial) {
    __shared__ float sred[4][64];
    int tid = threadIdx.x;
    int l = tid & 63;
    int wid = tid >> 6;
    int rowg = l >> 4;
    int lan16 = l & 15;

    f16x8 wA2_0 = __builtin_bit_cast(f16x8, *(const uint4*)&wf2[(size_t)(0 * 64 + l) * 8]);
    f16x8 wA2_1 = __builtin_bit_cast(f16x8, *(const uint4*)&wf2[(size_t)(1 * 64 + l) * 8]);
    f16x8 wA1_0{}, wA1_1{};
    float b1v[8];
    float b1a[4], b1b[4], tva[4], tvb_[4];
    if (FIRST) {
#pragma unroll
        for (int i = 0; i < 8; ++i) b1v[i] = b1[rowg * 8 + i];
    } else {
        wA1_0 = __builtin_bit_cast(f16x8, *(const uint4*)&wf1[(size_t)(0 * 64 + l) * 8]);
        wA1_1 = __builtin_bit_cast(f16x8, *(const uint4*)&wf1[(size_t)(1 * 64 + l) * 8]);
#pragma unroll
        for (int r = 0; r < 4; ++r) {
            b1a[r] = b1[rowg * 4 + r];
            b1b[r] = b1[16 + rowg * 4 + r];
            tva[r] = tv[rowg * 4 + r];
            tvb_[r] = tv[16 + rowg * 4 + r];
        }
    }
    float b2a[4], b2b[4];
#pragma unroll
    for (int r = 0; r < 4; ++r) {
        b2a[r] = b2[rowg * 4 + r];
        b2b[r] = b2[16 + rowg * 4 + r];
    }
    float sa[4] = {0.f, 0.f, 0.f, 0.f}, sb[4] = {0.f, 0.f, 0.f, 0.f};
    float qa[4] = {0.f, 0.f, 0.f, 0.f}, qb[4] = {0.f, 0.f, 0.f, 0.f};

    int gw = (blockIdx.x * 256 + tid) >> 6;
    int ngw = (gridDim.x * 256) >> 6;
    for (int t = gw; t < NN / 16; t += ngw) {
        int n0 = t * 16;
        int node = n0 + lan16;
        int r0 = rowptr[node], r1 = rowptr[node + 1];
        // gather: self + neighbors, packed-f16 accumulate, 4 independent chains
        uint4 su = *(const uint4*)(hsrc + (size_t)node * 32 + rowg * 8);
        f16x8 acc0 = __builtin_bit_cast(f16x8, su);
        f16x8 acc1{}, acc2{}, acc3{};
        int e = r0;
        for (; e + 4 <= r1; e += 4) {
            int s0 = colidx[e], s1 = colidx[e + 1], s2 = colidx[e + 2], s3 = colidx[e + 3];
            uint4 u0 = *(const uint4*)(hsrc + (size_t)s0 * 32 + rowg * 8);
            uint4 u1 = *(const uint4*)(hsrc + (size_t)s1 * 32 + rowg * 8);
            uint4 u2 = *(const uint4*)(hsrc + (size_t)s2 * 32 + rowg * 8);
            uint4 u3 = *(const uint4*)(hsrc + (size_t)s3 * 32 + rowg * 8);
            acc0 += __builtin_bit_cast(f16x8, u0);
            acc1 += __builtin_bit_cast(f16x8, u1);
            acc2 += __builtin_bit_cast(f16x8, u2);
            acc3 += __builtin_bit_cast(f16x8, u3);
        }
        if (e + 2 <= r1) {
            int s0 = colidx[e], s1 = colidx[e + 1];
            uint4 u0 = *(const uint4*)(hsrc + (size_t)s0 * 32 + rowg * 8);
            uint4 u1 = *(const uint4*)(hsrc + (size_t)s1 * 32 + rowg * 8);
            acc1 += __builtin_bit_cast(f16x8, u0);
            acc2 += __builtin_bit_cast(f16x8, u1);
            e += 2;
        }
        if (e < r1) {
            uint4 u0 = *(const uint4*)(hsrc + (size_t)colidx[e] * 32 + rowg * 8);
            acc3 += __builtin_bit_cast(f16x8, u0);
        }
        f16x8 af = (acc0 + acc1) + (acc2 + acc3);   // agg^T B-frag
        f16x8 frag;
        if (FIRST) {
#pragma unroll
            for (int i = 0; i < 8; ++i)
                frag[i] = (_Float16)fmaxf((float)af[i] + b1v[i], 0.f);
        } else {
            float cf = (float)(r1 - r0 + 1);
            f32x4 ca, cb;
#pragma unroll
            for (int r = 0; r < 4; ++r) {
                ca[r] = fmaf(cf, tva[r], b1a[r]);
                cb[r] = fmaf(cf, tvb_[r], b1b[r]);
            }
            ca = __builtin_amdgcn_mfma_f32_16x16x32_f16(wA1_0, af, ca, 0, 0, 0);
            cb = __builtin_amdgcn_mfma_f32_16x16x32_f16(wA1_1, af, cb, 0, 0, 0);
#pragma unroll
            for (int i = 0; i < 4; ++i) {
                frag[i] = (_Float16)fmaxf(ca[i], 0.f);
                frag[4 + i] = (_Float16)fmaxf(cb[i], 0.f);
            }
        }
        f32x4 ha, hb;
#pragma unroll
        for (int r = 0; r < 4; ++r) { ha[r] = b2a[r]; hb[r] = b2b[r]; }
        ha = __builtin_amdgcn_mfma_f32_16x16x32_f16(wA2_0, frag, ha, 0, 0, 0);
        hb = __builtin_amdgcn_mfma_f32_16x16x32_f16(wA2_1, frag, hb, 0, 0, 0);
        __half oa[4], ob[4];
#pragma unroll
        for (int r = 0; r < 4; ++r) {
            float va = fmaxf(ha[r], 0.f);
            float vb = fmaxf(hb[r], 0.f);
            sa[r] += va; qa[r] += va * va;
            sb[r] += vb; qb[r] += vb * vb;
            oa[r] = __float2half_rn(va);
            ob[r] = __float2half_rn(vb);
        }
        *(uint2*)(hdst + (size_t)node * 32 + rowg * 4) = *(const uint2*)oa;
        *(uint2*)(hdst + (size_t)node * 32 + 16 + rowg * 4) = *(const uint2*)ob;
    }
    // stats: reduce across the 16-lane node dimension (once per kernel)
#pragma unroll
    for (int r = 0; r < 4; ++r) {
#pragma unroll
        for (int off = 1; off < 16; off <<= 1) {
            sa[r] += __shfl_xor(sa[r], off, 64);
            sb[r] += __shfl_xor(sb[r], off, 64);
            qa[r] += __shfl_xor(qa[r], off, 64);
            qb[r] += __shfl_xor(qb[r], off, 64);
        }
    }
    if (lan16 == 0) {
#pragma unroll
        for (int r = 0; r < 4; ++r) {
            sred[wid][rowg * 4 + r] = sa[r];
            sred[wid][16 + rowg * 4 + r] = sb[r];
            sred[wid][32 + rowg * 4 + r] = qa[r];
            sred[wid][48 + rowg * 4 + r] = qb[r];
        }
    }
    __syncthreads();
    if (tid < 64) {
        float s = sred[0][tid] + sred[1][tid] + sred[2][tid] + sred[3][tid];
        partial[(size_t)blockIdx.x * 64 + tid] = s;
    }
}

// ---------------- finalize BN stats -> affine s,t (1 block/channel) ----------------
__global__ __launch_bounds__(256) void k_reduce(const float* __restrict__ partial, int nblocks,
                                                const float* __restrict__ g, const float* __restrict__ bt,
                                                float* __restrict__ aff) {
    int c = blockIdx.x;
    int t = threadIdx.x;
    double s = 0.0, q = 0.0;
    for (int b = t; b < nblocks; b += 256) {
        s += (double)partial[(size_t)b * 64 + c];
        q += (double)partial[(size_t)b * 64 + 32 + c];
    }
    __shared__ double shs[256], shq[256];
    shs[t] = s; shq[t] = q;
    __syncthreads();
    for (int off = 128; off; off >>= 1) {
        if (t < off) { shs[t] += shs[t + off]; shq[t] += shq[t + off]; }
        __syncthreads();
    }
    if (t == 0) {
        double mean = shs[0] / (double)NN;
        double var = shq[0] / (double)NN - mean * mean;
        float r = (float)rsqrt(var + 1e-5);
        float sv = g[c] * r;
        aff[c] = sv;
        aff[32 + c] = bt[c] - (float)mean * sv;
    }
}

// ---------------- pooling (xd_batch sorted -> run-length + atomics) ----------------
__global__ __launch_bounds__(256) void k_pool(const __half* __restrict__ h,
                                              const int* __restrict__ batch,
                                              float* __restrict__ ps) {
    int lane = threadIdx.x & 31;
    int g = threadIdx.x >> 5;
    const int chunk = (NN + gridDim.x - 1) / gridDim.x;
    int s0 = blockIdx.x * chunk;
    int s1 = min(NN, s0 + chunk);
    int curb = -1;
    float acc = 0.f;
    for (int i = s0 + g; i < s1; i += 8) {
        int b = batch[i];
        if (b != curb) {
            if (curb >= 0) atomicAdd(&ps[curb * 32 + lane], acc);
            acc = 0.f;
            curb = b;
        }
        acc += __half2float(h[(size_t)i * 32 + lane]);
    }
    if (curb >= 0) atomicAdd(&ps[curb * 32 + lane], acc);
}

__device__ int lowerb(const int* a, int n, int key) {
    int lo = 0, hi = n;
    while (lo < hi) {
        int m = (lo + hi) >> 1;
        if (a[m] < key) lo = m + 1;
        else hi = m;
    }
    return lo;
}

__global__ void k_counts(const int* __restrict__ batch, int* __restrict__ cnt) {
    int b = blockIdx.x * blockDim.x + threadIdx.x;
    if (b < BB) cnt[b] = lowerb(batch, NN, b + 1) - lowerb(batch, NN, b);
}

// ---------------- xdv = ReLU(pooled' @ fcd_w + fcd_b) ----------------
__global__ __launch_bounds__(128) void k_xdv(const float* __restrict__ ps,
                                             const int* __restrict__ cnt,
                                             const float* __restrict__ aff,
                                             const float* __restrict__ w,
                                             const float* __restrict__ bb,
                                             float* __restrict__ xdv) {
    int b = blockIdx.x;
    int j = threadIdx.x;
    __shared__ float p[32];
    if (j < 32) p[j] = aff[j] * ps[b * 32 + j] + (float)cnt[b] * aff[32 + j];
    __syncthreads();
    float acc = bb[j];
#pragma unroll
    for (int c = 0; c < 32; ++c) acc += p[c] * w[c * 128 + j];
    xdv[b * 128 + j] = fmaxf(acc, 0.f);
}

// ---------------- conv branch ----------------
__global__ void k_kT(const float* __restrict__ ck, float* __restrict__ kT) {
    int i = blockIdx.x;
    int t = threadIdx.x;
    int o = t >> 3, k = t & 7;
    kT[(size_t)i * 256 + t] = ck[(size_t)o * (LL * KK) + (size_t)i * KK + k];
}

// Bucket-sorted phase 1 with 8-deep load batching (8 independent kT loads in flight).
__global__ __launch_bounds__(256) void k_conv(const int* __restrict__ xt,
                                              const float* __restrict__ kT,
                                              const float* __restrict__ emb,
                                              const float* __restrict__ cb,
                                              float* __restrict__ cbuf) {
    __shared__ float S[VOCAB * 256];        // 26.6 KB
    __shared__ unsigned short order[LL];    // 2 KB
    __shared__ int scnt[VOCAB], soff[VOCAB + 1], bcur2[VOCAB];
    int t = threadIdx.x;
    int b = blockIdx.x;
    if (t < VOCAB) { scnt[t] = 0; bcur2[t] = 0; }
    __syncthreads();
    const int* row = xt + (size_t)b * LL;
    int vi[4];
#pragma unroll
    for (int j = 0; j < 4; ++j) {
        int i = t * 4 + j;
        if (i < LL) {
            vi[j] = row[i];
            atomicAdd(&scnt[vi[j]], 1);
        } else vi[j] = -1;
    }
    __syncthreads();
    if (t == 0) {
        int run = 0;
#pragma unroll
        for (int v = 0; v < VOCAB; ++v) { soff[v] = run; run += scnt[v]; }
        soff[VOCAB] = LL;
    }
    __syncthreads();
#pragma unroll
    for (int j = 0; j < 4; ++j) {
        if (vi[j] >= 0) {
            int pos = atomicAdd(&bcur2[vi[j]], 1);
            order[soff[vi[j]] + pos] = (unsigned short)(t * 4 + j);
        }
    }
    __syncthreads();
    // phase 1: S[v][t] = sum over bucket_v of kT[i*256+t]; 8 loads in flight per iter
    for (int v = 0; v < VOCAB; ++v) {
        int e0 = soff[v], e1 = soff[v + 1];
        float s0 = 0.f, s1 = 0.f, s2 = 0.f, s3 = 0.f;
        float s4 = 0.f, s5 = 0.f, s6 = 0.f, s7 = 0.f;
        int e = e0;
        for (; e + 8 <= e1; e += 8) {
            int i0 = order[e], i1 = order[e + 1], i2 = order[e + 2], i3 = order[e + 3];
            int i4 = order[e + 4], i5 = order[e + 5], i6 = order[e + 6], i7 = order[e + 7];
            float v0 = kT[(size_t)i0 * 256 + t];
            float v1 = kT[(size_t)i1 * 256 + t];
            float v2 = kT[(size_t)i2 * 256 + t];
            float v3 = kT[(size_t)i3 * 256 + t];
            float v4 = kT[(size_t)i4 * 256 + t];
            float v5 = kT[(size_t)i5 * 256 + t];
            float v6 = kT[(size_t)i6 * 256 + t];
            float v7 = kT[(size_t)i7 * 256 + t];
            s0 += v0; s1 += v1; s2 += v2; s3 += v3;
            s4 += v4; s5 += v5; s6 += v6; s7 += v7;
        }
        if (e + 4 <= e1) {
            int i0 = order[e], i1 = order[e + 1], i2 = order[e + 2], i3 = order[e + 3];
            float v0 = kT[(size_t)i0 * 256 + t];
            float v1 = kT[(size_t)i1 * 256 + t];
            float v2 = kT[(size_t)i2 * 256 + t];
            float v3 = kT[(size_t)i3 * 256 + t];
            s4 += v0; s5 += v1; s6 += v2; s7 += v3;
            e += 4;
        }
        if (e + 2 <= e1) {
            int i0 = order[e], i1 = order[e + 1];
            s1 += kT[(size_t)i0 * 256 + t];
            s2 += kT[(size_t)i1 * 256 + t];
            e += 2;
        }
        if (e < e1) s0 += kT[(size_t)order[e] * 256 + t];
        S[v * 256 + t] = ((s0 + s1) + (s2 + s3)) + ((s4 + s5) + (s6 + s7));
    }
    __syncthreads();
    // phase 2: out[o,h] = cb[o] + sum_v sum_k S[v,o,k] * emb[v,h+k]
    int h = t & 127, half = t >> 7;
    if (h < 121) {
        float acc[16];
        int o0 = half * 16;
#pragma unroll
        for (int o = 0; o < 16; ++o) acc[o] = cb[o0 + o];
        for (int v = 0; v < VOCAB; ++v) {
            float e[8];
#pragma unroll
            for (int k = 0; k < 8; ++k) e[k] = emb[v * EMBD + h + k];   // L1-resident
#pragma unroll
            for (int o = 0; o < 16; ++o) {
                float a = acc[o];
#pragma unroll
                for (int k = 0; k < 8; ++k) a += S[v * 256 + (o0 + o) * 8 + k] * e[k];
                acc[o] = a;
            }
        }
#pragma unroll
        for (int o = 0; o < 16; ++o)
            cbuf[(size_t)b * CF + (size_t)(o0 + o) * 121 + h] = acc[o];
    }
}

// ---------------- bias init ----------------
__global__ void k_binit(const float* __restrict__ bias, float* __restrict__ out, int mask) {
    int i = blockIdx.x * blockDim.x + threadIdx.x;
    out[i] = bias[i & mask];
}

// ---------------- xtv += c_tile @ w_tile (split-K, LDS-tiled, atomic accumulate) ----------------
__global__ __launch_bounds__(256) void k_xtv(const float* __restrict__ c,
                                             const float* __restrict__ w,
                                             float* __restrict__ xtv) {
    __shared__ float ct[16][484];
    int rb = blockIdx.x >> 3, kc = blockIdx.x & 7;
    int b0 = rb * 16, k0 = kc * 484;
    int tid = threadIdx.x;
#pragma unroll
    for (int r = 0; r < 16; ++r)
        for (int k = tid; k < 484; k += 256)
            ct[r][k] = c[(size_t)(b0 + r) * CF + k0 + k];
    __syncthreads();
    int j = tid & 127, rh = tid >> 7;
    float acc[8];
#pragma unroll
    for (int r = 0; r < 8; ++r) acc[r] = 0.f;
    const float2* ct2 = (const float2*)&ct[0][0];
    for (int k2 = 0; k2 < 242; ++k2) {
        float w0 = w[(size_t)(k0 + 2 * k2) * 128 + j];
        float w1 = w[(size_t)(k0 + 2 * k2 + 1) * 128 + j];
#pragma unroll
        for (int r = 0; r < 8; ++r) {
            float2 cv = ct2[(rh * 8 + r) * 242 + k2];
            acc[r] = fmaf(cv.x, w0, fmaf(cv.y, w1, acc[r]));
        }
    }
#pragma unroll
    for (int r = 0; r < 8; ++r)
        atomicAdd(&xtv[(size_t)(b0 + rh * 8 + r) * 128 + j], acc[r]);
}

// ---------------- classifier ----------------
__global__ __launch_bounds__(1024) void k_cls1(const float* __restrict__ xdv,
                                               const float* __restrict__ xtv,
                                               const float* __restrict__ w,
                                               const float* __restrict__ bb,
                                               float* __restrict__ h1) {
    __shared__ float X[8][256];
    int j = threadIdx.x;
    int b0 = blockIdx.x * 8;
    for (int idx = j; idx < 8 * 256; idx += 1024) {
        int r = idx >> 8, k = idx & 255;
        X[r][k] = (k < 128) ? xdv[(b0 + r) * 128 + k] : xtv[(b0 + r) * 128 + (k - 128)];
    }
    __syncthreads();
    float acc[8];
#pragma unroll
    for (int r = 0; r < 8; ++r) acc[r] = bb[j];
    for (int k = 0; k < 256; ++k) {
        float wv = w[(size_t)k * 1024 + j];
#pragma unroll
        for (int r = 0; r < 8; ++r) acc[r] += X[r][k] * wv;
    }
#pragma unroll
    for (int r = 0; r < 8; ++r) h1[(size_t)(b0 + r) * 1024 + j] = fmaxf(acc[r], 0.f);
}

__global__ __launch_bounds__(256) void k_cls2(const float* __restrict__ h1,
                                              const float* __restrict__ w,
                                              float* __restrict__ h2) {
    __shared__ float X[8][256];
    int rb = blockIdx.x >> 2, kc = blockIdx.x & 3;
    int b0 = rb * 8, k0 = kc * 256;
    int tid = threadIdx.x;
#pragma unroll
    for (int r = 0; r < 8; ++r)
        X[r][tid] = h1[(size_t)(b0 + r) * 1024 + k0 + tid];
    __syncthreads();
    int j = tid;
    float acc[8];
#pragma unroll
    for (int r = 0; r < 8; ++r) acc[r] = 0.f;
    const float2* X2 = (const float2*)&X[0][0];
    for (int k2 = 0; k2 < 128; ++k2) {
        float w0 = w[(size_t)(k0 + 2 * k2) * 256 + j];
        float w1 = w[(size_t)(k0 + 2 * k2 + 1) * 256 + j];
#pragma unroll
        for (int r = 0; r < 8; ++r) {
            float2 xv = X2[r * 128 + k2];
            acc[r] = fmaf(xv.x, w0, fmaf(xv.y, w1, acc[r]));
        }
    }
#pragma unroll
    for (int r = 0; r < 8; ++r)
        atomicAdd(&h2[(size_t)(b0 + r) * 256 + j], acc[r]);
}

__global__ __launch_bounds__(256) void k_cls3(const float* __restrict__ h2,
                                              const float* __restrict__ w,
                                              const float* __restrict__ bb,
                                              const float* __restrict__ y,
                                              float* __restrict__ dout) {
    int lane = threadIdx.x & 63;
    int b = (blockIdx.x * blockDim.x + threadIdx.x) >> 6;
    if (b >= BB) return;
    float acc = 0.f;
    for (int k = lane; k < 256; k += 64) acc += fmaxf(h2[(size_t)b * 256 + k], 0.f) * w[k];
#pragma unroll
    for (int off = 32; off; off >>= 1) acc += __shfl_xor(acc, off, 64);
    if (lane == 0) dout[b] = acc + bb[0];
    if (lane == 1) dout[BB + b] = y[b];
}

// ---------------- launch ----------------
extern "C" void kernel_launch(void* const* d_in, const int* in_sizes, int n_in,
                              void* d_out, int out_size, void* d_ws, size_t ws_size,
                              hipStream_t stream) {
    const float* xd = (const float*)d_in[0];
    const int* ei = (const int*)d_in[1];
    const int* batch = (const int*)d_in[2];
    const int* xt = (const int*)d_in[3];
    const float* y = (const float*)d_in[4];
    const float* g1w1 = (const float*)d_in[5];
    const float* g1b1 = (const float*)d_in[6];
    const float* g1w2 = (const float*)d_in[7];
    const float* g1b2 = (const float*)d_in[8];
    const float* grw1 = (const float*)d_in[9];
    const float* grb1 = (const float*)d_in[10];
    const float* grw2 = (const float*)d_in[11];
    const float* grb2 = (const float*)d_in[12];
    const float* bng = (const float*)d_in[13];
    const float* bnb = (const float*)d_in[14];
    const float* fcdw = (const float*)d_in[15];
    const float* fcdb = (const float*)d_in[16];
    const float* emb = (const float*)d_in[17];
    const float* convk = (const float*)d_in[18];
    const float* convb = (const float*)d_in[19];
    const float* fctw = (const float*)d_in[20];
    const float* fctb = (const float*)d_in[21];
    const float* cw1 = (const float*)d_in[22];
    const float* cb1 = (const float*)d_in[23];
    const float* cw2 = (const float*)d_in[24];
    const float* cb2 = (const float*)d_in[25];
    const float* cw3 = (const float*)d_in[26];
    const float* cb3 = (const float*)d_in[27];

    const int* src = ei;
    const int* dst = ei + EE;

    size_t off = 0;
    auto alloc = [&](size_t bytes) {
        size_t o = off;
        off = (off + bytes + 255) & ~(size_t)255;
        return o;
    };
    char* ws = (char*)d_ws;
    size_t o_rp = alloc(4ull * (NN + 1));
    size_t o_col = alloc(4ull * EE);
    size_t o_bc = alloc(4ull * 256);
    size_t o_bb = alloc(4ull * 256);
    size_t o_ha = alloc(2ull * NN * 32);
    size_t o_hb = alloc(2ull * NN * 32);
    size_t o_eb = alloc(8ull * NB * ESLOT);
    size_t o_part = alloc(4ull * 2048 * 64);
    size_t o_aff = alloc(4ull * 64);
    size_t o_w1f = alloc(2ull * 2048);
    size_t o_wf1 = alloc(2ull * 1024);
    size_t o_wf2 = alloc(2ull * 1024);
    size_t o_tv = alloc(4ull * 32);
    size_t o_ps = alloc(4ull * BB * 32);
    size_t o_cnt = alloc(4ull * BB);
    size_t o_xdv = alloc(4ull * BB * 128);
    size_t o_kT = alloc(4ull * LL * 256);
    size_t o_c = alloc(4ull * BB * CF);
    size_t o_xtv = alloc(4ull * BB * 128);
    size_t o_h1 = alloc(4ull * BB * 1024);
    size_t o_h2 = alloc(4ull * BB * 256);

    int* rp = (int*)(ws + o_rp);
    int* col = (int*)(ws + o_col);
    int* bcur = (int*)(ws + o_bc);
    int* bbase = (int*)(ws + o_bb);
    __half* ha = (__half*)(ws + o_ha);
    __half* hb = (__half*)(ws + o_hb);
    unsigned long long* ebuf = (unsigned long long*)(ws + o_eb);
    float* part = (float*)(ws + o_part);
    float* aff = (float*)(ws + o_aff);
    __half* w1f = (__half*)(ws + o_w1f);
    __half* wf1 = (__half*)(ws + o_wf1);
    __half* wf2 = (__half*)(ws + o_wf2);
    float* tvb = (float*)(ws + o_tv);
    float* ps = (float*)(ws + o_ps);
    int* cnt = (int*)(ws + o_cnt);
    float* xdv = (float*)(ws + o_xdv);
    float* kT = (float*)(ws + o_kT);
    float* cbuf = (float*)(ws + o_c);
    float* xtv = (float*)(ws + o_xtv);
    float* h1 = (float*)(ws + o_h1);
    float* h2 = (float*)(ws + o_h2);
    float* dout = (float*)d_out;

    // --- CSR build (bucketed two-pass) ---
    hipMemsetAsync(bcur, 0, 4ull * NB, stream);
    k_bscatter<<<977, 256, 0, stream>>>(src, dst, bcur, ebuf);
    k_bscan<<<1, 256, 0, stream>>>(bcur, bbase);
    k_build<<<NB, 256, 0, stream>>>(ebuf, bbase, bcur, rp, col);

    // --- GIN layers (fused gather + swapped MFMA mlp) ---
    k_pfrag<<<1, 64, 0, stream>>>(g1w1, w1f);
    k_p1<<<2048, 256, 0, stream>>>(xd, w1f, ha);

    // layer 1
    k_wfrag<1><<<1, 64, 0, stream>>>(aff, g1w1, g1w2, wf1, wf2, tvb);
    k_mlp<1><<<2048, 256, 0, stream>>>(ha, rp, col, wf1, wf2, tvb, g1b1, g1b2, hb, part);
    k_reduce<<<32, 256, 0, stream>>>(part, 2048, bng, bnb, aff);

    const __half* srcbuf = hb;
    __half* dstbuf = ha;
    for (int i = 0; i < 4; ++i) {
        k_wfrag<0><<<1, 64, 0, stream>>>(aff, grw1 + (size_t)i * 1024, grw2 + (size_t)i * 1024,
                                         wf1, wf2, tvb);
        k_mlp<0><<<2048, 256, 0, stream>>>(srcbuf, rp, col, wf1, wf2, tvb,
                                           grb1 + (size_t)i * 32, grb2 + (size_t)i * 32,
                                           dstbuf, part);
        k_reduce<<<32, 256, 0, stream>>>(part, 2048, bng + (i + 1) * 32, bnb + (i + 1) * 32, aff);
        const __half* tmp = srcbuf;
        srcbuf = dstbuf;
        dstbuf = (__half*)tmp;
    }
    // after loop: srcbuf == layer-5 output, aff == layer-5 affine

    // --- pooling + xdv ---
    hipMemsetAsync(ps, 0, 4ull * BB * 32, stream);
    k_pool<<<1024, 256, 0, stream>>>(srcbuf, batch, ps);
    k_counts<<<4, 256, 0, stream>>>(batch, cnt);
    k_xdv<<<BB, 128, 0, stream>>>(ps, cnt, aff, fcdw, fcdb, xdv);

    // --- conv branch ---
    k_kT<<<LL, 256, 0, stream>>>(convk, kT);
    k_conv<<<BB, 256, 0, stream>>>(xt, kT, emb, convb, cbuf);
    k_binit<<<BB * 128 / 256, 256, 0, stream>>>(fctb, xtv, 127);
    k_xtv<<<512, 256, 0, stream>>>(cbuf, fctw, xtv);

    // --- classifier ---
    k_cls1<<<BB / 8, 1024, 0, stream>>>(xdv, xtv, cw1, cb1, h1);
    k_binit<<<BB * 256 / 256, 256, 0, stream>>>(cb2, h2, 255);
    k_cls2<<<512, 256, 0, stream>>>(h1, cw2, h2);
    k_cls3<<<256, 256, 0, stream>>>(h2, cw3, cb3, y, dout);
}